// Round 2
// baseline (1246.649 us; speedup 1.0000x reference)
//
#include <hip/hip_runtime.h>

#define BT 8192     // B*L
#define SEQL 512
#define DIM 768
#define HID 384
#define NG 1536     // 4*HID

using US = unsigned short;
typedef __bf16 bf16x8 __attribute__((ext_vector_type(8)));
typedef float f32x4 __attribute__((ext_vector_type(4)));

__device__ __forceinline__ float b2f(US u) {
  union { unsigned u; float f; } x; x.u = ((unsigned)u) << 16; return x.f;
}
__device__ __forceinline__ US f2b(float f) {
  union { float f; unsigned u; } x; x.f = f;
  unsigned r = x.u + 0x7FFFu + ((x.u >> 16) & 1u);
  return (US)(r >> 16);
}
__device__ __forceinline__ float fsig(float x) { return 1.f / (1.f + __expf(-x)); }
__device__ __forceinline__ float ftanh(float x) { return 1.f - 2.f / (__expf(2.f * x) + 1.f); }

__device__ __forceinline__ void gload16(const void* g, void* l) {
  __builtin_amdgcn_global_load_lds((const __attribute__((address_space(1))) unsigned*)g,
                                   (__attribute__((address_space(3))) unsigned*)l, 16, 0, 0);
}

// ---------------- compaction ----------------
__global__ void scan_k(const int* __restrict__ valid, int* __restrict__ dest) {
  __shared__ int s[SEQL];
  int b = blockIdx.x, l = threadIdx.x;
  int v = (valid[b * SEQL + l] == 1) ? 1 : 0;
  s[l] = v;
  __syncthreads();
  for (int off = 1; off < SEQL; off <<= 1) {
    int t = (l >= off) ? s[l - off] : 0;
    __syncthreads();
    s[l] += t;
    __syncthreads();
  }
  dest[b * SEQL + l] = v ? (s[l] - 1) : -1;
}

// compaction + f32 -> bf16 conversion
__global__ __launch_bounds__(256) void scatter_k(const float* __restrict__ seq,
                                                 const int* __restrict__ dest,
                                                 US* __restrict__ xc) {
  int idx = blockIdx.x * 256 + threadIdx.x;  // BT*192 float4 chunks
  int p = idx / 192, c = idx - p * 192;
  int d = dest[p];
  if (d < 0) return;
  int b = p >> 9;
  float4 v = ((const float4*)seq)[(size_t)p * 192 + c];
  ushort4 o;
  o.x = f2b(v.x); o.y = f2b(v.y); o.z = f2b(v.z); o.w = f2b(v.w);
  ((ushort4*)xc)[(size_t)(b * SEQL + d) * 192 + c] = o;
}

// ---------------- gate pre-GEMM: G[wi] = xc @ Wih[wi]^T + (bih+bhh) ----------------
// A (xc) bf16 via global_load_lds; B (Wih, f32) reg-staged with f32->bf16 convert.
__global__ __launch_bounds__(256) void gate_gemm_k(
    const US* __restrict__ xc, const float* __restrict__ Wih,
    const float* __restrict__ bih, const float* __restrict__ bhh,
    US* __restrict__ G) {
  int wi = blockIdx.z;
  const float* W = Wih + (size_t)wi * NG * DIM;
  int m0 = blockIdx.x * 128, n0 = blockIdx.y * 128;
  __shared__ alignas(16) US As[128 * 64];
  __shared__ alignas(16) US Bs[128 * 64];
  __shared__ float biasS[128];
  int tid = threadIdx.x, lane = tid & 63, wid = tid >> 6;
  int wm = wid >> 1, wn = wid & 1;
  if (tid < 128) {
    int gc = wi * NG + n0 + tid;
    biasS[tid] = bih[gc] + bhh[gc];
  }
  int r_in = lane >> 3;
  int cb = (lane & 7) * 16;
  f32x4 acc[4][4] = {};
  for (int k0 = 0; k0 < DIM; k0 += 64) {
    __syncthreads();
#pragma unroll
    for (int c = 0; c < 4; ++c) {
      int chk = wid * 4 + c;
      int row = chk * 8 + r_in;
      gload16((const char*)xc + ((size_t)(m0 + row) * DIM + k0) * 2 + cb, (char*)As + chk * 1024);
    }
#pragma unroll
    for (int j = 0; j < 8; ++j) {
      int q = j * 256 + tid;        // 128 rows x 16 float4 chunks
      int row = q >> 4;
      int c4 = (q & 15) << 2;
      float4 v = *(const float4*)(W + (size_t)(n0 + row) * DIM + k0 + c4);
      ushort4 o;
      o.x = f2b(v.x); o.y = f2b(v.y); o.z = f2b(v.z); o.w = f2b(v.w);
      *(ushort4*)&Bs[row * 64 + c4] = o;
    }
    __syncthreads();
#pragma unroll
    for (int kk = 0; kk < 2; ++kk) {
      bf16x8 a[4], b[4];
#pragma unroll
      for (int i = 0; i < 4; ++i)
        a[i] = *(const bf16x8*)&As[(wm * 64 + i * 16 + (lane & 15)) * 64 + kk * 32 + (lane >> 4) * 8];
#pragma unroll
      for (int i = 0; i < 4; ++i)
        b[i] = *(const bf16x8*)&Bs[(wn * 64 + i * 16 + (lane & 15)) * 64 + kk * 32 + (lane >> 4) * 8];
#pragma unroll
      for (int mi = 0; mi < 4; ++mi)
#pragma unroll
        for (int ni = 0; ni < 4; ++ni)
          acc[mi][ni] = __builtin_amdgcn_mfma_f32_16x16x32_bf16(a[mi], b[ni], acc[mi][ni], 0, 0, 0);
    }
  }
  US* Gw = G + (size_t)wi * BT * NG;
#pragma unroll
  for (int mi = 0; mi < 4; ++mi) {
    int rb = m0 + wm * 64 + mi * 16 + ((lane >> 4) << 2);
#pragma unroll
    for (int ni = 0; ni < 4; ++ni) {
      int cl = wn * 64 + ni * 16 + (lane & 15);
#pragma unroll
      for (int r = 0; r < 4; ++r)
        Gw[(size_t)(rb + r) * NG + n0 + cl] = f2b(acc[mi][ni][r] + biasS[cl]);
    }
  }
}

// ---------------- LSTM step 0 (h=0): pointwise only ----------------
__global__ __launch_bounds__(384) void step0_k(const US* __restrict__ G, float* __restrict__ C,
                                               US* __restrict__ hn, int dir) {
  int wi = blockIdx.z;
  int half = wi + 1;
  int dlt = dir ? half : -half;  // j = 0 fwd, j = w-1 bwd
  int p = blockIdx.x, hidx = threadIdx.x;
  int l = p & (SEQL - 1);
  const US* Gw = G + (size_t)wi * BT * NG;
  float c = 0.f, h = 0.f;
  int t = l + dlt;
  if ((unsigned)t < (unsigned)SEQL) {
    size_t gr = (size_t)(p + dlt) * NG;
    float gi = b2f(Gw[gr + hidx]);
    float gg = b2f(Gw[gr + 2 * HID + hidx]);
    float go = b2f(Gw[gr + 3 * HID + hidx]);
    c = fsig(gi) * ftanh(gg);
    h = fsig(go) * ftanh(c);
  }
  C[(size_t)wi * BT * HID + (size_t)p * HID + hidx] = c;
  hn[(size_t)wi * BT * HID + (size_t)p * HID + hidx] = f2b(h);
}

// ---------------- LSTM step s>=1: fused h@Whh^T GEMM + pointwise ----------------
// N-tile = gathered {i,f,g,o} segments for one 32-wide h-block; wave frag sg == gate seg,
// so each thread holds all 4 gates for its (row, h) -> pointwise stays in registers.
__global__ __launch_bounds__(256) void step_k(
    const float* __restrict__ Whh, const US* __restrict__ G,
    float* __restrict__ C, const US* __restrict__ hcur,
    US* __restrict__ hnxt, US* __restrict__ Outs,
    int dir, int s, int wi0) {
  int wi = wi0 + blockIdx.z;
  int w = 2 * wi + 3, half = wi + 1;
  int j = dir ? (w - 1 - s) : s;
  int dlt = j - half;
  bool fin = (s == w - 1);
  const float* Wc = Whh + (size_t)wi * NG * HID;
  const US* Gw = G + (size_t)wi * BT * NG;
  float* Cw = C + (size_t)wi * BT * HID;
  const US* hc = hcur + (size_t)wi * BT * HID;
  US* hn = hnxt + (size_t)wi * BT * HID;
  US* Ow = Outs + (size_t)wi * BT * DIM + (dir ? HID : 0);
  int m0 = blockIdx.x * 128, hb = blockIdx.y;
  __shared__ alignas(16) US As[128 * 64];
  __shared__ alignas(16) US Bs[128 * 64];
  int tid = threadIdx.x, lane = tid & 63, wid = tid >> 6;
  int wm = wid >> 1, wn = wid & 1;
  int r_in = lane >> 3, cb = (lane & 7) * 16;
  f32x4 acc[4][4] = {};
  for (int k0 = 0; k0 < HID; k0 += 64) {
    __syncthreads();
#pragma unroll
    for (int c = 0; c < 4; ++c) {
      int chk = wid * 4 + c;
      int row = chk * 8 + r_in;
      gload16((const char*)hc + ((size_t)(m0 + row) * HID + k0) * 2 + cb, (char*)As + chk * 1024);
    }
#pragma unroll
    for (int j2 = 0; j2 < 8; ++j2) {
      int q = j2 * 256 + tid;
      int row = q >> 4;
      int c4 = (q & 15) << 2;
      int src = (row >> 5) * HID + hb * 32 + (row & 31);  // gathered gate rows
      float4 v = *(const float4*)(Wc + (size_t)src * HID + k0 + c4);
      ushort4 o;
      o.x = f2b(v.x); o.y = f2b(v.y); o.z = f2b(v.z); o.w = f2b(v.w);
      *(ushort4*)&Bs[row * 64 + c4] = o;
    }
    __syncthreads();
#pragma unroll
    for (int kk = 0; kk < 2; ++kk) {
      bf16x8 a[4], b[4];
#pragma unroll
      for (int i = 0; i < 4; ++i)
        a[i] = *(const bf16x8*)&As[(wm * 64 + i * 16 + (lane & 15)) * 64 + kk * 32 + (lane >> 4) * 8];
#pragma unroll
      for (int sg = 0; sg < 4; ++sg)
        b[sg] = *(const bf16x8*)&Bs[(sg * 32 + wn * 16 + (lane & 15)) * 64 + kk * 32 + (lane >> 4) * 8];
#pragma unroll
      for (int mi = 0; mi < 4; ++mi)
#pragma unroll
        for (int sg = 0; sg < 4; ++sg)
          acc[mi][sg] = __builtin_amdgcn_mfma_f32_16x16x32_bf16(a[mi], b[sg], acc[mi][sg], 0, 0, 0);
    }
  }
  int hh = wn * 16 + (lane & 15);
  int hidx = hb * 32 + hh;
#pragma unroll
  for (int mi = 0; mi < 4; ++mi) {
#pragma unroll
    for (int r = 0; r < 4; ++r) {
      int p = m0 + wm * 64 + mi * 16 + ((lane >> 4) << 2) + r;
      int l = p & (SEQL - 1);
      float hval;
      if ((unsigned)(l + dlt) < (unsigned)SEQL) {
        size_t gr = (size_t)(p + dlt) * NG;
        float gi = acc[mi][0][r] + b2f(Gw[gr + hidx]);
        float gf = acc[mi][1][r] + b2f(Gw[gr + HID + hidx]);
        float gg = acc[mi][2][r] + b2f(Gw[gr + 2 * HID + hidx]);
        float go = acc[mi][3][r] + b2f(Gw[gr + 3 * HID + hidx]);
        size_t ci = (size_t)p * HID + hidx;
        float c = fsig(gf) * Cw[ci] + fsig(gi) * ftanh(gg);
        Cw[ci] = c;
        hval = fsig(go) * ftanh(c);
      } else {
        hval = b2f(hc[(size_t)p * HID + hidx]);  // masked: carry state forward
      }
      if (fin) Ow[(size_t)p * DIM + hidx] = f2b(hval);
      else hn[(size_t)p * HID + hidx] = f2b(hval);
    }
  }
}

// ---------------- attention over 3 windows + KAN head ----------------
__global__ __launch_bounds__(256) void attn_kan_k(
    const US* __restrict__ Outs, const float* __restrict__ coef,
    const float* __restrict__ kbias, float* __restrict__ out) {
  int p = blockIdx.x, tid = threadIdx.x;
  int lane = tid & 63, wid = tid >> 6;
  __shared__ float red[11][4];
  float o0[3], o1[3], o2[3], q[3];
#pragma unroll
  for (int c = 0; c < 3; ++c) {
    int i = tid + 256 * c;
    o0[c] = b2f(Outs[(size_t)p * DIM + i]);
    o1[c] = b2f(Outs[(size_t)(BT + p) * DIM + i]);
    o2[c] = b2f(Outs[(size_t)(2 * BT + p) * DIM + i]);
    q[c] = o0[c] + o1[c] + o2[c];
  }
  float d0 = 0.f, d1 = 0.f, d2 = 0.f;
#pragma unroll
  for (int c = 0; c < 3; ++c) { d0 += q[c] * o0[c]; d1 += q[c] * o1[c]; d2 += q[c] * o2[c]; }
#pragma unroll
  for (int off = 32; off; off >>= 1) {
    d0 += __shfl_down(d0, off);
    d1 += __shfl_down(d1, off);
    d2 += __shfl_down(d2, off);
  }
  if (lane == 0) { red[0][wid] = d0; red[1][wid] = d1; red[2][wid] = d2; }
  __syncthreads();
  const float scl = 0.03608439182435161f;  // 1/sqrt(768)
  float s0 = (red[0][0] + red[0][1] + red[0][2] + red[0][3]) * scl;
  float s1 = (red[1][0] + red[1][1] + red[1][2] + red[1][3]) * scl;
  float s2 = (red[2][0] + red[2][1] + red[2][2] + red[2][3]) * scl;
  float mx = fmaxf(s0, fmaxf(s1, s2));
  float e0 = __expf(s0 - mx), e1 = __expf(s1 - mx), e2 = __expf(s2 - mx);
  float inv = 1.f / (e0 + e1 + e2);
  e0 *= inv; e1 *= inv; e2 *= inv;
  float acc[11];
#pragma unroll
  for (int o = 0; o < 11; ++o) acc[o] = 0.f;
#pragma unroll
  for (int c = 0; c < 3; ++c) {
    int i = tid + 256 * c;
    float sq = q[c] + e0 * o0[c] + e1 * o1[c] + e2 * o2[c];
#pragma unroll
    for (int g = 0; g < 3; ++g) {
      float sn, cs;
      __sincosf(sq * (float)(g + 1), &sn, &cs);
#pragma unroll
      for (int o = 0; o < 11; ++o)
        acc[o] += cs * coef[(size_t)(o * 3 + g) * DIM + i] +
                  sn * coef[(size_t)(33 + o * 3 + g) * DIM + i];
    }
  }
  __syncthreads();
#pragma unroll
  for (int o = 0; o < 11; ++o) {
    float v = acc[o];
#pragma unroll
    for (int off = 32; off; off >>= 1) v += __shfl_down(v, off);
    if (lane == 0) red[o][wid] = v;
  }
  __syncthreads();
  if (tid < 11)
    out[(size_t)p * 11 + tid] =
        red[tid][0] + red[tid][1] + red[tid][2] + red[tid][3] + kbias[tid];
}

extern "C" void kernel_launch(void* const* d_in, const int* in_sizes, int n_in,
                              void* d_out, int out_size, void* d_ws, size_t ws_size,
                              hipStream_t stream) {
  const float* seq = (const float*)d_in[0];
  const float* Wih[2] = {(const float*)d_in[1], (const float*)d_in[5]};
  const float* Whh[2] = {(const float*)d_in[2], (const float*)d_in[6]};
  const float* bih[2] = {(const float*)d_in[3], (const float*)d_in[7]};
  const float* bhh[2] = {(const float*)d_in[4], (const float*)d_in[8]};
  const float* coef = (const float*)d_in[9];
  const float* kbias = (const float*)d_in[10];
  const int* valid = (const int*)d_in[11];

  char* ws = (char*)d_ws;
  constexpr size_t SZ_XC = (size_t)BT * DIM * 2;        // 12.58 MB compacted x (bf16)
  constexpr size_t SZ_DEST = (size_t)BT * 4;
  constexpr size_t SZ_G = (size_t)3 * BT * NG * 2;      // 75.5 MB gates (bf16)
  constexpr size_t SZ_C = (size_t)3 * BT * HID * 4;     // 37.7 MB cell state (f32)
  constexpr size_t SZ_H = (size_t)3 * BT * HID * 2;     // 18.9 MB per h ping-pong (bf16)
  constexpr size_t SZ_OUTS = (size_t)3 * BT * DIM * 2;  // 37.7 MB window outputs (bf16)
  constexpr size_t OFF_XC = 0;
  constexpr size_t OFF_DEST = OFF_XC + SZ_XC;
  constexpr size_t OFF_G = OFF_DEST + SZ_DEST;
  constexpr size_t OFF_C = OFF_G + SZ_G;
  constexpr size_t OFF_H0 = OFF_C + SZ_C;
  constexpr size_t OFF_H1 = OFF_H0 + SZ_H;
  constexpr size_t OFF_OUTS = OFF_H1 + SZ_H;
  constexpr size_t NEED = OFF_OUTS + SZ_OUTS;  // ~201.4 MB (proven to fit in round 1)
  if (ws_size < NEED) return;

  US* xc = (US*)(ws + OFF_XC);
  int* dest = (int*)(ws + OFF_DEST);
  US* G = (US*)(ws + OFF_G);
  float* C = (float*)(ws + OFF_C);
  US* h0 = (US*)(ws + OFF_H0);
  US* h1 = (US*)(ws + OFF_H1);
  US* Outs = (US*)(ws + OFF_OUTS);
  float* out = (float*)d_out;

  hipMemsetAsync(xc, 0, SZ_XC, stream);
  scan_k<<<16, SEQL, 0, stream>>>(valid, dest);
  scatter_k<<<(BT * 192) / 256, 256, 0, stream>>>(seq, dest, xc);

  for (int dir = 0; dir < 2; ++dir) {
    gate_gemm_k<<<dim3(64, 12, 3), 256, 0, stream>>>(xc, Wih[dir], bih[dir], bhh[dir], G);
    step0_k<<<dim3(BT, 1, 3), HID, 0, stream>>>(G, C, h1, dir);  // writes h1, C fully
    for (int s = 1; s < 7; ++s) {
      int nact = (s < 3) ? 3 : ((s < 5) ? 2 : 1);
      int wi0 = 3 - nact;
      US* hcur = (s & 1) ? h1 : h0;
      US* hnxt = (s & 1) ? h0 : h1;
      step_k<<<dim3(64, 12, nact), 256, 0, stream>>>(Whh[dir], G, C, hcur, hnxt, Outs,
                                                     dir, s, wi0);
    }
  }
  attn_kan_k<<<BT, 256, 0, stream>>>(Outs, coef, kbias, out);
}

// Round 3
// 1142.658 us; speedup vs baseline: 1.0910x; 1.0910x over previous
//
#include <hip/hip_runtime.h>

#define BT 8192     // B*L
#define SEQL 512
#define DIM 768
#define HID 384
#define NG 1536     // 4*HID

using US = unsigned short;
typedef __bf16 bf16x8 __attribute__((ext_vector_type(8)));
typedef float f32x4 __attribute__((ext_vector_type(4)));

__device__ __forceinline__ float b2f(US u) {
  union { unsigned u; float f; } x; x.u = ((unsigned)u) << 16; return x.f;
}
__device__ __forceinline__ US f2b(float f) {
  __bf16 h = (__bf16)f;                 // compiler emits proper cvt (RNE)
  union { __bf16 h; US u; } x; x.h = h; return x.u;
}
__device__ __forceinline__ float fsig(float x) { return 1.f / (1.f + __expf(-x)); }
__device__ __forceinline__ float ftanh(float x) { return 1.f - 2.f / (__expf(2.f * x) + 1.f); }

__device__ __forceinline__ void gload16(const void* g, void* l) {
  __builtin_amdgcn_global_load_lds((const __attribute__((address_space(1))) unsigned*)g,
                                   (__attribute__((address_space(3))) unsigned*)l, 16, 0, 0);
}

// swizzled LDS read of a bf16x8 fragment: tile is [128 rows][128 bytes],
// phys_byte(row, colb) = row*128 + (colb ^ ((row&7)<<4))
__device__ __forceinline__ bf16x8 lds_frag(const US* base, int row, int colb, int swz) {
  return *(const bf16x8*)((const char*)base + row * 128 + (colb ^ swz));
}

// ---------------- compaction ----------------
__global__ void scan_k(const int* __restrict__ valid, int* __restrict__ dest) {
  __shared__ int s[SEQL];
  int b = blockIdx.x, l = threadIdx.x;
  int v = (valid[b * SEQL + l] == 1) ? 1 : 0;
  s[l] = v;
  __syncthreads();
  for (int off = 1; off < SEQL; off <<= 1) {
    int t = (l >= off) ? s[l - off] : 0;
    __syncthreads();
    s[l] += t;
    __syncthreads();
  }
  dest[b * SEQL + l] = v ? (s[l] - 1) : -1;
}

// compaction + f32 -> bf16 conversion
__global__ __launch_bounds__(256) void scatter_k(const float* __restrict__ seq,
                                                 const int* __restrict__ dest,
                                                 US* __restrict__ xc) {
  int idx = blockIdx.x * 256 + threadIdx.x;  // BT*192 float4 chunks
  int p = idx / 192, c = idx - p * 192;
  int d = dest[p];
  if (d < 0) return;
  int b = p >> 9;
  float4 v = ((const float4*)seq)[(size_t)p * 192 + c];
  ushort4 o;
  o.x = f2b(v.x); o.y = f2b(v.y); o.z = f2b(v.z); o.w = f2b(v.w);
  ((ushort4*)xc)[(size_t)(b * SEQL + d) * 192 + c] = o;
}

// ---------------- gate pre-GEMM: G[dr][wi] = xc @ Wih[dr][wi]^T + (bih+bhh) ----------------
__global__ __launch_bounds__(256) void gate_gemm_k(
    const US* __restrict__ xc,
    const float* __restrict__ WihF, const float* __restrict__ WihB,
    const float* __restrict__ bihF, const float* __restrict__ bihB,
    const float* __restrict__ bhhF, const float* __restrict__ bhhB,
    US* __restrict__ G, size_t gStride, int dirBase) {
  int zi = blockIdx.z;
  int wi = zi % 3, dr = dirBase + zi / 3;
  const float* Wih = dr ? WihB : WihF;
  const float* bih = dr ? bihB : bihF;
  const float* bhh = dr ? bhhB : bhhF;
  const float* W = Wih + (size_t)wi * NG * DIM;
  US* Gw = G + (size_t)dr * gStride + (size_t)wi * BT * NG;
  int m0 = blockIdx.x * 128, n0 = blockIdx.y * 128;
  __shared__ alignas(16) US As[128 * 64];
  __shared__ alignas(16) US Bs[128 * 64];
  __shared__ float biasS[128];
  int tid = threadIdx.x, lane = tid & 63, wid = tid >> 6;
  int wm = wid >> 1, wn = wid & 1;
  if (tid < 128) {
    int gc = wi * NG + n0 + tid;
    biasS[tid] = bih[gc] + bhh[gc];
  }
  int r_in = lane >> 3;
  int cb = (lane & 7) * 16;
  int cb_src = cb ^ (r_in << 4);       // pre-swizzled global source column (bytes)
  int swz = (lane & 7) << 4;           // read-side swizzle (row&7 == lane&7 for frag rows)
  f32x4 acc[4][4] = {};
  for (int k0 = 0; k0 < DIM; k0 += 64) {
    __syncthreads();
#pragma unroll
    for (int c = 0; c < 4; ++c) {
      int chk = wid * 4 + c;
      int row = chk * 8 + r_in;
      gload16((const char*)xc + ((size_t)(m0 + row) * DIM + k0) * 2 + cb_src,
              (char*)As + chk * 1024);
    }
#pragma unroll
    for (int j = 0; j < 8; ++j) {
      int q = j * 256 + tid;           // 128 rows x 16 (4xf32) chunks
      int row = q >> 4;
      int c4 = (q & 15) << 2;          // f32 element offset in row
      float4 v = *(const float4*)(W + (size_t)(n0 + row) * DIM + k0 + c4);
      ushort4 o;
      o.x = f2b(v.x); o.y = f2b(v.y); o.z = f2b(v.z); o.w = f2b(v.w);
      *(ushort4*)((char*)Bs + row * 128 + ((c4 * 2) ^ ((row & 7) << 4))) = o;
    }
    __syncthreads();
#pragma unroll
    for (int kk = 0; kk < 2; ++kk) {
      int colb = kk * 64 + (lane >> 4) * 16;
      bf16x8 a[4], b[4];
#pragma unroll
      for (int i = 0; i < 4; ++i)
        a[i] = lds_frag(As, wm * 64 + i * 16 + (lane & 15), colb, swz);
#pragma unroll
      for (int i = 0; i < 4; ++i)
        b[i] = lds_frag(Bs, wn * 64 + i * 16 + (lane & 15), colb, swz);
#pragma unroll
      for (int mi = 0; mi < 4; ++mi)
#pragma unroll
        for (int ni = 0; ni < 4; ++ni)
          acc[mi][ni] = __builtin_amdgcn_mfma_f32_16x16x32_bf16(a[mi], b[ni], acc[mi][ni], 0, 0, 0);
    }
  }
#pragma unroll
  for (int mi = 0; mi < 4; ++mi) {
    int rb = m0 + wm * 64 + mi * 16 + ((lane >> 4) << 2);
#pragma unroll
    for (int ni = 0; ni < 4; ++ni) {
      int cl = wn * 64 + ni * 16 + (lane & 15);
#pragma unroll
      for (int r = 0; r < 4; ++r)
        Gw[(size_t)(rb + r) * NG + n0 + cl] = f2b(acc[mi][ni][r] + biasS[cl]);
    }
  }
}

// ---------------- LSTM step 0 (h=0): pointwise only ----------------
__global__ __launch_bounds__(384) void step0_k(const US* __restrict__ G, float* __restrict__ C,
                                               US* __restrict__ hn,
                                               size_t gStride, size_t cStride, size_t hStride,
                                               int dirBase) {
  int zi = blockIdx.z;
  int wi = zi % 3, dr = dirBase + zi / 3;
  int half = wi + 1;
  int dlt = dr ? half : -half;  // j = 0 fwd, j = w-1 bwd
  int p = blockIdx.x, hidx = threadIdx.x;
  int l = p & (SEQL - 1);
  const US* Gw = G + (size_t)dr * gStride + (size_t)wi * BT * NG;
  float c = 0.f, h = 0.f;
  int t = l + dlt;
  if ((unsigned)t < (unsigned)SEQL) {
    size_t gr = (size_t)(p + dlt) * NG;
    float gi = b2f(Gw[gr + hidx]);
    float gg = b2f(Gw[gr + 2 * HID + hidx]);
    float go = b2f(Gw[gr + 3 * HID + hidx]);
    c = fsig(gi) * ftanh(gg);
    h = fsig(go) * ftanh(c);
  }
  size_t o = (size_t)wi * BT * HID + (size_t)p * HID + hidx;
  C[(size_t)dr * cStride + o] = c;
  hn[(size_t)dr * hStride + o] = f2b(h);
}

// ---------------- LSTM step s>=1: fused h@Whh^T GEMM + pointwise ----------------
__global__ __launch_bounds__(256) void step_k(
    const float* __restrict__ WhhF, const float* __restrict__ WhhB,
    const US* __restrict__ G, float* __restrict__ C,
    const US* __restrict__ hcur, US* __restrict__ hnxt, US* __restrict__ Outs,
    int s, int wi0, int nact,
    size_t gStride, size_t cStride, size_t hStride, int dirBase) {
  int zi = blockIdx.z;
  int wi = wi0 + zi % nact, dr = dirBase + zi / nact;
  int w = 2 * wi + 3, half = wi + 1;
  int j = dr ? (w - 1 - s) : s;
  int dlt = j - half;
  bool fin = (s == w - 1);
  const float* Whh = dr ? WhhB : WhhF;
  const float* Wc = Whh + (size_t)wi * NG * HID;
  const US* Gw = G + (size_t)dr * gStride + (size_t)wi * BT * NG;
  float* Cw = C + (size_t)dr * cStride + (size_t)wi * BT * HID;
  const US* hc = hcur + (size_t)dr * hStride + (size_t)wi * BT * HID;
  US* hn = hnxt + (size_t)dr * hStride + (size_t)wi * BT * HID;
  US* Ow = Outs + (size_t)wi * BT * DIM + (dr ? HID : 0);
  int m0 = blockIdx.x * 128, hb = blockIdx.y;
  __shared__ alignas(16) US As[128 * 64];
  __shared__ alignas(16) US Bs[128 * 64];
  int tid = threadIdx.x, lane = tid & 63, wid = tid >> 6;
  int wm = wid >> 1, wn = wid & 1;
  int r_in = lane >> 3, cb = (lane & 7) * 16;
  int cb_src = cb ^ (r_in << 4);
  int swz = (lane & 7) << 4;
  f32x4 acc[4][4] = {};
  for (int k0 = 0; k0 < HID; k0 += 64) {
    __syncthreads();
#pragma unroll
    for (int c = 0; c < 4; ++c) {
      int chk = wid * 4 + c;
      int row = chk * 8 + r_in;
      gload16((const char*)hc + ((size_t)(m0 + row) * HID + k0) * 2 + cb_src,
              (char*)As + chk * 1024);
    }
#pragma unroll
    for (int j2 = 0; j2 < 8; ++j2) {
      int q = j2 * 256 + tid;
      int row = q >> 4;
      int c4 = (q & 15) << 2;
      int src = (row >> 5) * HID + hb * 32 + (row & 31);  // gathered gate rows
      float4 v = *(const float4*)(Wc + (size_t)src * HID + k0 + c4);
      ushort4 o;
      o.x = f2b(v.x); o.y = f2b(v.y); o.z = f2b(v.z); o.w = f2b(v.w);
      *(ushort4*)((char*)Bs + row * 128 + ((c4 * 2) ^ ((row & 7) << 4))) = o;
    }
    __syncthreads();
#pragma unroll
    for (int kk = 0; kk < 2; ++kk) {
      int colb = kk * 64 + (lane >> 4) * 16;
      bf16x8 a[4], b[4];
#pragma unroll
      for (int i = 0; i < 4; ++i)
        a[i] = lds_frag(As, wm * 64 + i * 16 + (lane & 15), colb, swz);
#pragma unroll
      for (int sg = 0; sg < 4; ++sg)
        b[sg] = lds_frag(Bs, sg * 32 + wn * 16 + (lane & 15), colb, swz);
#pragma unroll
      for (int mi = 0; mi < 4; ++mi)
#pragma unroll
        for (int sg = 0; sg < 4; ++sg)
          acc[mi][sg] = __builtin_amdgcn_mfma_f32_16x16x32_bf16(a[mi], b[sg], acc[mi][sg], 0, 0, 0);
    }
  }
  int hh = wn * 16 + (lane & 15);
  int hidx = hb * 32 + hh;
#pragma unroll
  for (int mi = 0; mi < 4; ++mi) {
#pragma unroll
    for (int r = 0; r < 4; ++r) {
      int p = m0 + wm * 64 + mi * 16 + ((lane >> 4) << 2) + r;
      int l = p & (SEQL - 1);
      float hval;
      if ((unsigned)(l + dlt) < (unsigned)SEQL) {
        size_t gr = (size_t)(p + dlt) * NG;
        float gi = acc[mi][0][r] + b2f(Gw[gr + hidx]);
        float gf = acc[mi][1][r] + b2f(Gw[gr + HID + hidx]);
        float gg = acc[mi][2][r] + b2f(Gw[gr + 2 * HID + hidx]);
        float go = acc[mi][3][r] + b2f(Gw[gr + 3 * HID + hidx]);
        size_t ci = (size_t)p * HID + hidx;
        float c = fsig(gf) * Cw[ci] + fsig(gi) * ftanh(gg);
        Cw[ci] = c;
        hval = fsig(go) * ftanh(c);
      } else {
        hval = b2f(hc[(size_t)p * HID + hidx]);  // masked: carry state forward
      }
      if (fin) Ow[(size_t)p * DIM + hidx] = f2b(hval);
      else hn[(size_t)p * HID + hidx] = f2b(hval);
    }
  }
}

// ---------------- attention over 3 windows + KAN head ----------------
__global__ __launch_bounds__(256) void attn_kan_k(
    const US* __restrict__ Outs, const float* __restrict__ coef,
    const float* __restrict__ kbias, float* __restrict__ out) {
  int p = blockIdx.x, tid = threadIdx.x;
  int lane = tid & 63, wid = tid >> 6;
  __shared__ float red[11][4];
  float o0[3], o1[3], o2[3], q[3];
#pragma unroll
  for (int c = 0; c < 3; ++c) {
    int i = tid + 256 * c;
    o0[c] = b2f(Outs[(size_t)p * DIM + i]);
    o1[c] = b2f(Outs[(size_t)(BT + p) * DIM + i]);
    o2[c] = b2f(Outs[(size_t)(2 * BT + p) * DIM + i]);
    q[c] = o0[c] + o1[c] + o2[c];
  }
  float d0 = 0.f, d1 = 0.f, d2 = 0.f;
#pragma unroll
  for (int c = 0; c < 3; ++c) { d0 += q[c] * o0[c]; d1 += q[c] * o1[c]; d2 += q[c] * o2[c]; }
#pragma unroll
  for (int off = 32; off; off >>= 1) {
    d0 += __shfl_down(d0, off);
    d1 += __shfl_down(d1, off);
    d2 += __shfl_down(d2, off);
  }
  if (lane == 0) { red[0][wid] = d0; red[1][wid] = d1; red[2][wid] = d2; }
  __syncthreads();
  const float scl = 0.03608439182435161f;  // 1/sqrt(768)
  float s0 = (red[0][0] + red[0][1] + red[0][2] + red[0][3]) * scl;
  float s1 = (red[1][0] + red[1][1] + red[1][2] + red[1][3]) * scl;
  float s2 = (red[2][0] + red[2][1] + red[2][2] + red[2][3]) * scl;
  float mx = fmaxf(s0, fmaxf(s1, s2));
  float e0 = __expf(s0 - mx), e1 = __expf(s1 - mx), e2 = __expf(s2 - mx);
  float inv = 1.f / (e0 + e1 + e2);
  e0 *= inv; e1 *= inv; e2 *= inv;
  float acc[11];
#pragma unroll
  for (int o = 0; o < 11; ++o) acc[o] = 0.f;
#pragma unroll
  for (int c = 0; c < 3; ++c) {
    int i = tid + 256 * c;
    float sq = q[c] + e0 * o0[c] + e1 * o1[c] + e2 * o2[c];
#pragma unroll
    for (int g = 0; g < 3; ++g) {
      float sn, cs;
      __sincosf(sq * (float)(g + 1), &sn, &cs);
#pragma unroll
      for (int o = 0; o < 11; ++o)
        acc[o] += cs * coef[(size_t)(o * 3 + g) * DIM + i] +
                  sn * coef[(size_t)(33 + o * 3 + g) * DIM + i];
    }
  }
  __syncthreads();
#pragma unroll
  for (int o = 0; o < 11; ++o) {
    float v = acc[o];
#pragma unroll
    for (int off = 32; off; off >>= 1) v += __shfl_down(v, off);
    if (lane == 0) red[o][wid] = v;
  }
  __syncthreads();
  if (tid < 11)
    out[(size_t)p * 11 + tid] =
        red[tid][0] + red[tid][1] + red[tid][2] + red[tid][3] + kbias[tid];
}

extern "C" void kernel_launch(void* const* d_in, const int* in_sizes, int n_in,
                              void* d_out, int out_size, void* d_ws, size_t ws_size,
                              hipStream_t stream) {
  const float* seq = (const float*)d_in[0];
  const float* WihF = (const float*)d_in[1];
  const float* WhhF = (const float*)d_in[2];
  const float* bihF = (const float*)d_in[3];
  const float* bhhF = (const float*)d_in[4];
  const float* WihB = (const float*)d_in[5];
  const float* WhhB = (const float*)d_in[6];
  const float* bihB = (const float*)d_in[7];
  const float* bhhB = (const float*)d_in[8];
  const float* coef = (const float*)d_in[9];
  const float* kbias = (const float*)d_in[10];
  const int* valid = (const int*)d_in[11];

  constexpr size_t SZ_XC = (size_t)BT * DIM * 2;
  constexpr size_t SZ_DEST = (size_t)BT * 4;
  constexpr size_t GE = (size_t)3 * BT * NG;    // per-dir G elems (US)
  constexpr size_t CE = (size_t)3 * BT * HID;   // per-dir C elems (f32)
  constexpr size_t HE = (size_t)3 * BT * HID;   // per-dir h elems (US)
  constexpr size_t SZ_OUTS = (size_t)3 * BT * DIM * 2;
  auto need = [](int nd) {
    return SZ_XC + SZ_DEST + (size_t)nd * (GE * 2 + CE * 4 + HE * 2 * 2) + SZ_OUTS;
  };
  if (ws_size < need(1)) return;
  const int ndir = (ws_size >= need(2)) ? 2 : 1;

  char* ws = (char*)d_ws;
  US* xc = (US*)ws;                          ws += SZ_XC;
  int* dest = (int*)ws;                      ws += SZ_DEST;
  US* G = (US*)ws;                           ws += (size_t)ndir * GE * 2;
  float* C = (float*)ws;                     ws += (size_t)ndir * CE * 4;
  US* h0 = (US*)ws;                          ws += (size_t)ndir * HE * 2;
  US* h1 = (US*)ws;                          ws += (size_t)ndir * HE * 2;
  US* Outs = (US*)ws;
  float* out = (float*)d_out;

  hipMemsetAsync(xc, 0, SZ_XC, stream);
  scan_k<<<16, SEQL, 0, stream>>>(valid, dest);
  scatter_k<<<(BT * 192) / 256, 256, 0, stream>>>(seq, dest, xc);

  if (ndir == 2) {
    // both directions batched into z
    gate_gemm_k<<<dim3(64, 12, 6), 256, 0, stream>>>(xc, WihF, WihB, bihF, bihB, bhhF, bhhB,
                                                     G, GE, 0);
    step0_k<<<dim3(BT, 1, 6), HID, 0, stream>>>(G, C, h1, GE, CE, HE, 0);
    for (int s = 1; s < 7; ++s) {
      int nact = (s < 3) ? 3 : ((s < 5) ? 2 : 1);
      int wi0 = 3 - nact;
      US* hcur = (s & 1) ? h1 : h0;
      US* hnxt = (s & 1) ? h0 : h1;
      step_k<<<dim3(64, 12, nact * 2), 256, 0, stream>>>(WhhF, WhhB, G, C, hcur, hnxt, Outs,
                                                         s, wi0, nact, GE, CE, HE, 0);
    }
  } else {
    for (int dir = 0; dir < 2; ++dir) {
      gate_gemm_k<<<dim3(64, 12, 3), 256, 0, stream>>>(xc, WihF, WihB, bihF, bihB, bhhF, bhhB,
                                                       G, 0, dir);
      step0_k<<<dim3(BT, 1, 3), HID, 0, stream>>>(G, C, h1, 0, 0, 0, dir);
      for (int s = 1; s < 7; ++s) {
        int nact = (s < 3) ? 3 : ((s < 5) ? 2 : 1);
        int wi0 = 3 - nact;
        US* hcur = (s & 1) ? h1 : h0;
        US* hnxt = (s & 1) ? h0 : h1;
        step_k<<<dim3(64, 12, nact), 256, 0, stream>>>(WhhF, WhhB, G, C, hcur, hnxt, Outs,
                                                       s, wi0, nact, 0, 0, 0, dir);
      }
    }
  }
  attn_kan_k<<<BT, 256, 0, stream>>>(Outs, coef, kbias, out);
}

// Round 4
// 1044.465 us; speedup vs baseline: 1.1936x; 1.0940x over previous
//
#include <hip/hip_runtime.h>

#define BT 8192     // B*L
#define SEQL 512
#define DIM 768
#define HID 384
#define NG 1536     // 4*HID

using US = unsigned short;
typedef __bf16 bf16x8 __attribute__((ext_vector_type(8)));
typedef float f32x4 __attribute__((ext_vector_type(4)));

__device__ __forceinline__ float b2f(US u) {
  union { unsigned u; float f; } x; x.u = ((unsigned)u) << 16; return x.f;
}
__device__ __forceinline__ US f2b(float f) {
  __bf16 h = (__bf16)f;
  union { __bf16 h; US u; } x; x.h = h; return x.u;
}
__device__ __forceinline__ float fsig(float x) { return 1.f / (1.f + __expf(-x)); }
__device__ __forceinline__ float ftanh(float x) { return 1.f - 2.f / (__expf(2.f * x) + 1.f); }

__device__ __forceinline__ void gload16(const void* g, void* l) {
  __builtin_amdgcn_global_load_lds((const __attribute__((address_space(1))) unsigned*)g,
                                   (__attribute__((address_space(3))) unsigned*)l, 16, 0, 0);
}

// swizzled LDS read: tile [128 rows][128 bytes], phys = row*128 + (colb ^ ((row&7)<<4))
__device__ __forceinline__ bf16x8 lds_frag(const US* base, int row, int colb, int swz) {
  return *(const bf16x8*)((const char*)base + row * 128 + (colb ^ swz));
}

// ---------------- weight pre-conversion ----------------
// Wih: flat f32 -> bf16 copy, per dir ([3][NG][DIM])
__global__ __launch_bounds__(256) void convW_ih_k(const float* __restrict__ WihF,
                                                  const float* __restrict__ WihB,
                                                  US* __restrict__ WihC) {
  int d = blockIdx.z;
  const float* src = d ? WihB : WihF;
  size_t idx = (size_t)blockIdx.x * 256 + threadIdx.x;  // 884736 float4 chunks per dir
  float4 v = ((const float4*)src)[idx];
  ushort4 o;
  o.x = f2b(v.x); o.y = f2b(v.y); o.z = f2b(v.z); o.w = f2b(v.w);
  ((ushort4*)WihC)[(size_t)d * 884736 + idx] = o;
}

// Whh: gather into step-tile order [dir][wi][hb][r=sg*32+hh][K] bf16
__global__ __launch_bounds__(256) void convW_hh_k(const float* __restrict__ WhhF,
                                                  const float* __restrict__ WhhB,
                                                  US* __restrict__ WhhC) {
  int d = blockIdx.z;
  const float* src = d ? WhhB : WhhF;
  size_t idx = (size_t)blockIdx.x * 256 + threadIdx.x;  // 442368 chunks per dir
  int c4 = (int)(idx % 96) * 4;
  int rr = (int)(idx / 96);
  int r = rr & 127;
  int hb = (rr >> 7) % 12;
  int wi = rr / (128 * 12);
  int srow = (r >> 5) * HID + hb * 32 + (r & 31);
  float4 v = *(const float4*)(src + ((size_t)wi * NG + srow) * HID + c4);
  ushort4 o;
  o.x = f2b(v.x); o.y = f2b(v.y); o.z = f2b(v.z); o.w = f2b(v.w);
  *(ushort4*)(WhhC + ((size_t)d * 3 * 12 * 128 + (size_t)rr) * HID + c4) = o;
}

// ---------------- compaction ----------------
__global__ void scan_k(const int* __restrict__ valid, int* __restrict__ dest) {
  __shared__ int s[SEQL];
  int b = blockIdx.x, l = threadIdx.x;
  int v = (valid[b * SEQL + l] == 1) ? 1 : 0;
  s[l] = v;
  __syncthreads();
  for (int off = 1; off < SEQL; off <<= 1) {
    int t = (l >= off) ? s[l - off] : 0;
    __syncthreads();
    s[l] += t;
    __syncthreads();
  }
  dest[b * SEQL + l] = v ? (s[l] - 1) : -1;
}

__global__ __launch_bounds__(256) void scatter_k(const float* __restrict__ seq,
                                                 const int* __restrict__ dest,
                                                 US* __restrict__ xc) {
  int idx = blockIdx.x * 256 + threadIdx.x;  // BT*192 float4 chunks
  int p = idx / 192, c = idx - p * 192;
  int d = dest[p];
  if (d < 0) return;
  int b = p >> 9;
  float4 v = ((const float4*)seq)[(size_t)p * 192 + c];
  ushort4 o;
  o.x = f2b(v.x); o.y = f2b(v.y); o.z = f2b(v.z); o.w = f2b(v.w);
  ((ushort4*)xc)[(size_t)(b * SEQL + d) * 192 + c] = o;
}

// ---------------- gate pre-GEMM: G[dr][wi] = xc @ Wih[dr][wi]^T + (bih+bhh) ----------------
template <bool PRE>
__global__ __launch_bounds__(256) void gate_gemm_k(
    const US* __restrict__ xc,
    const float* __restrict__ WihF, const float* __restrict__ WihB,
    const US* __restrict__ WihC,
    const float* __restrict__ bihF, const float* __restrict__ bihB,
    const float* __restrict__ bhhF, const float* __restrict__ bhhB,
    US* __restrict__ G, size_t gStride, int dirBase) {
  int zi = blockIdx.z;
  int wi = zi % 3, dr = dirBase + zi / 3;
  const float* Wih = dr ? WihB : WihF;
  const float* bih = dr ? bihB : bihF;
  const float* bhh = dr ? bhhB : bhhF;
  const float* W = Wih + (size_t)wi * NG * DIM;
  const US* Wp = WihC + (size_t)(dr * 3 + wi) * NG * DIM;
  US* Gw = G + (size_t)dr * gStride + (size_t)wi * BT * NG;
  int m0 = blockIdx.x * 128, n0 = blockIdx.y * 128;
  __shared__ alignas(16) US As[128 * 64];
  __shared__ alignas(16) US Bs[128 * 64];
  __shared__ float biasS[128];
  int tid = threadIdx.x, lane = tid & 63, wid = tid >> 6;
  int wm = wid >> 1, wn = wid & 1;
  if (tid < 128) {
    int gc = wi * NG + n0 + tid;
    biasS[tid] = bih[gc] + bhh[gc];
  }
  int r_in = lane >> 3;
  int cb = (lane & 7) * 16;
  int cb_src = cb ^ (r_in << 4);   // pre-swizzled global source column (bytes)
  int swz = (lane & 7) << 4;       // read-side swizzle
  f32x4 acc[4][4] = {};
  for (int k0 = 0; k0 < DIM; k0 += 64) {
    __syncthreads();
#pragma unroll
    for (int c = 0; c < 4; ++c) {
      int chk = wid * 4 + c;
      int row = chk * 8 + r_in;
      gload16((const char*)xc + ((size_t)(m0 + row) * DIM + k0) * 2 + cb_src,
              (char*)As + chk * 1024);
      if constexpr (PRE)
        gload16((const char*)Wp + ((size_t)(n0 + row) * DIM + k0) * 2 + cb_src,
                (char*)Bs + chk * 1024);
    }
    if constexpr (!PRE) {
#pragma unroll
      for (int j = 0; j < 8; ++j) {
        int q = j * 256 + tid;
        int row = q >> 4;
        int c4 = (q & 15) << 2;
        float4 v = *(const float4*)(W + (size_t)(n0 + row) * DIM + k0 + c4);
        ushort4 o;
        o.x = f2b(v.x); o.y = f2b(v.y); o.z = f2b(v.z); o.w = f2b(v.w);
        *(ushort4*)((char*)Bs + row * 128 + ((c4 * 2) ^ ((row & 7) << 4))) = o;
      }
    }
    __syncthreads();
#pragma unroll
    for (int kk = 0; kk < 2; ++kk) {
      int colb = kk * 64 + (lane >> 4) * 16;
      bf16x8 a[4], b[4];
#pragma unroll
      for (int i = 0; i < 4; ++i)
        a[i] = lds_frag(As, wm * 64 + i * 16 + (lane & 15), colb, swz);
#pragma unroll
      for (int i = 0; i < 4; ++i)
        b[i] = lds_frag(Bs, wn * 64 + i * 16 + (lane & 15), colb, swz);
#pragma unroll
      for (int mi = 0; mi < 4; ++mi)
#pragma unroll
        for (int ni = 0; ni < 4; ++ni)
          acc[mi][ni] = __builtin_amdgcn_mfma_f32_16x16x32_bf16(a[mi], b[ni], acc[mi][ni], 0, 0, 0);
    }
  }
#pragma unroll
  for (int mi = 0; mi < 4; ++mi) {
    int rb = m0 + wm * 64 + mi * 16 + ((lane >> 4) << 2);
#pragma unroll
    for (int ni = 0; ni < 4; ++ni) {
      int cl = wn * 64 + ni * 16 + (lane & 15);
#pragma unroll
      for (int r = 0; r < 4; ++r)
        Gw[(size_t)(rb + r) * NG + n0 + cl] = f2b(acc[mi][ni][r] + biasS[cl]);
    }
  }
}

// ---------------- LSTM step 0 (h=0): pointwise only ----------------
__global__ __launch_bounds__(384) void step0_k(const US* __restrict__ G, float* __restrict__ C,
                                               US* __restrict__ hn,
                                               size_t gStride, size_t cStride, size_t hStride,
                                               int dirBase) {
  int zi = blockIdx.z;
  int wi = zi % 3, dr = dirBase + zi / 3;
  int half = wi + 1;
  int dlt = dr ? half : -half;
  int p = blockIdx.x, hidx = threadIdx.x;
  int l = p & (SEQL - 1);
  const US* Gw = G + (size_t)dr * gStride + (size_t)wi * BT * NG;
  float c = 0.f, h = 0.f;
  int t = l + dlt;
  if ((unsigned)t < (unsigned)SEQL) {
    size_t gr = (size_t)(p + dlt) * NG;
    float gi = b2f(Gw[gr + hidx]);
    float gg = b2f(Gw[gr + 2 * HID + hidx]);
    float go = b2f(Gw[gr + 3 * HID + hidx]);
    c = fsig(gi) * ftanh(gg);
    h = fsig(go) * ftanh(c);
  }
  size_t o = (size_t)wi * BT * HID + (size_t)p * HID + hidx;
  C[(size_t)dr * cStride + o] = c;
  hn[(size_t)dr * hStride + o] = f2b(h);
}

// ---------------- LSTM step s>=1: fused h@Whh^T GEMM + pointwise ----------------
template <bool PRE>
__global__ __launch_bounds__(256) void step_k(
    const float* __restrict__ WhhF, const float* __restrict__ WhhB,
    const US* __restrict__ WhhC,
    const US* __restrict__ G, float* __restrict__ C,
    const US* __restrict__ hcur, US* __restrict__ hnxt, US* __restrict__ Outs,
    int s, int wi0, int nact,
    size_t gStride, size_t cStride, size_t hStride, int dirBase) {
  int zi = blockIdx.z;
  int wi = wi0 + zi % nact, dr = dirBase + zi / nact;
  int w = 2 * wi + 3, half = wi + 1;
  int j = dr ? (w - 1 - s) : s;
  int dlt = j - half;
  bool fin = (s == w - 1);
  const float* Whh = dr ? WhhB : WhhF;
  const float* Wc = Whh + (size_t)wi * NG * HID;
  const US* Gw = G + (size_t)dr * gStride + (size_t)wi * BT * NG;
  float* Cw = C + (size_t)dr * cStride + (size_t)wi * BT * HID;
  const US* hc = hcur + (size_t)dr * hStride + (size_t)wi * BT * HID;
  US* hn = hnxt + (size_t)dr * hStride + (size_t)wi * BT * HID;
  US* Ow = Outs + (size_t)wi * BT * DIM + (dr ? HID : 0);
  int m0 = blockIdx.x * 128, hb = blockIdx.y;
  const US* Wp = WhhC + (size_t)((dr * 3 + wi) * 12 + hb) * 128 * HID;
  __shared__ alignas(16) US As[128 * 64];
  __shared__ alignas(16) US Bs[128 * 64];
  int tid = threadIdx.x, lane = tid & 63, wid = tid >> 6;
  int wm = wid >> 1, wn = wid & 1;
  int r_in = lane >> 3, cb = (lane & 7) * 16;
  int cb_src = cb ^ (r_in << 4);
  int swz = (lane & 7) << 4;
  f32x4 acc[4][4] = {};
  for (int k0 = 0; k0 < HID; k0 += 64) {
    __syncthreads();
#pragma unroll
    for (int c = 0; c < 4; ++c) {
      int chk = wid * 4 + c;
      int row = chk * 8 + r_in;
      gload16((const char*)hc + ((size_t)(m0 + row) * HID + k0) * 2 + cb_src,
              (char*)As + chk * 1024);
      if constexpr (PRE)
        gload16((const char*)Wp + ((size_t)row * HID + k0) * 2 + cb_src,
                (char*)Bs + chk * 1024);
    }
    if constexpr (!PRE) {
#pragma unroll
      for (int j2 = 0; j2 < 8; ++j2) {
        int q = j2 * 256 + tid;
        int row = q >> 4;
        int c4 = (q & 15) << 2;
        int src = (row >> 5) * HID + hb * 32 + (row & 31);
        float4 v = *(const float4*)(Wc + (size_t)src * HID + k0 + c4);
        ushort4 o;
        o.x = f2b(v.x); o.y = f2b(v.y); o.z = f2b(v.z); o.w = f2b(v.w);
        *(ushort4*)((char*)Bs + row * 128 + ((c4 * 2) ^ ((row & 7) << 4))) = o;
      }
    }
    __syncthreads();
#pragma unroll
    for (int kk = 0; kk < 2; ++kk) {
      int colb = kk * 64 + (lane >> 4) * 16;
      bf16x8 a[4], b[4];
#pragma unroll
      for (int i = 0; i < 4; ++i)
        a[i] = lds_frag(As, wm * 64 + i * 16 + (lane & 15), colb, swz);
#pragma unroll
      for (int sg = 0; sg < 4; ++sg)
        b[sg] = lds_frag(Bs, sg * 32 + wn * 16 + (lane & 15), colb, swz);
#pragma unroll
      for (int mi = 0; mi < 4; ++mi)
#pragma unroll
        for (int sg = 0; sg < 4; ++sg)
          acc[mi][sg] = __builtin_amdgcn_mfma_f32_16x16x32_bf16(a[mi], b[sg], acc[mi][sg], 0, 0, 0);
    }
  }
  int hh = wn * 16 + (lane & 15);
  int hidx = hb * 32 + hh;
#pragma unroll
  for (int mi = 0; mi < 4; ++mi) {
#pragma unroll
    for (int r = 0; r < 4; ++r) {
      int p = m0 + wm * 64 + mi * 16 + ((lane >> 4) << 2) + r;
      int l = p & (SEQL - 1);
      float hval;
      if ((unsigned)(l + dlt) < (unsigned)SEQL) {
        size_t gr = (size_t)(p + dlt) * NG;
        float gi = acc[mi][0][r] + b2f(Gw[gr + hidx]);
        float gf = acc[mi][1][r] + b2f(Gw[gr + HID + hidx]);
        float gg = acc[mi][2][r] + b2f(Gw[gr + 2 * HID + hidx]);
        float go = acc[mi][3][r] + b2f(Gw[gr + 3 * HID + hidx]);
        size_t ci = (size_t)p * HID + hidx;
        float c = fsig(gf) * Cw[ci] + fsig(gi) * ftanh(gg);
        Cw[ci] = c;
        hval = fsig(go) * ftanh(c);
      } else {
        hval = b2f(hc[(size_t)p * HID + hidx]);
      }
      if (fin) Ow[(size_t)p * DIM + hidx] = f2b(hval);
      else hn[(size_t)p * HID + hidx] = f2b(hval);
    }
  }
}

// ---------------- attention over 3 windows + KAN head ----------------
__global__ __launch_bounds__(256) void attn_kan_k(
    const US* __restrict__ Outs, const float* __restrict__ coef,
    const float* __restrict__ kbias, float* __restrict__ out) {
  int p = blockIdx.x, tid = threadIdx.x;
  int lane = tid & 63, wid = tid >> 6;
  __shared__ float red[11][4];
  float o0[3], o1[3], o2[3], q[3];
#pragma unroll
  for (int c = 0; c < 3; ++c) {
    int i = tid + 256 * c;
    o0[c] = b2f(Outs[(size_t)p * DIM + i]);
    o1[c] = b2f(Outs[(size_t)(BT + p) * DIM + i]);
    o2[c] = b2f(Outs[(size_t)(2 * BT + p) * DIM + i]);
    q[c] = o0[c] + o1[c] + o2[c];
  }
  float d0 = 0.f, d1 = 0.f, d2 = 0.f;
#pragma unroll
  for (int c = 0; c < 3; ++c) { d0 += q[c] * o0[c]; d1 += q[c] * o1[c]; d2 += q[c] * o2[c]; }
#pragma unroll
  for (int off = 32; off; off >>= 1) {
    d0 += __shfl_down(d0, off);
    d1 += __shfl_down(d1, off);
    d2 += __shfl_down(d2, off);
  }
  if (lane == 0) { red[0][wid] = d0; red[1][wid] = d1; red[2][wid] = d2; }
  __syncthreads();
  const float scl = 0.03608439182435161f;  // 1/sqrt(768)
  float s0 = (red[0][0] + red[0][1] + red[0][2] + red[0][3]) * scl;
  float s1 = (red[1][0] + red[1][1] + red[1][2] + red[1][3]) * scl;
  float s2 = (red[2][0] + red[2][1] + red[2][2] + red[2][3]) * scl;
  float mx = fmaxf(s0, fmaxf(s1, s2));
  float e0 = __expf(s0 - mx), e1 = __expf(s1 - mx), e2 = __expf(s2 - mx);
  float inv = 1.f / (e0 + e1 + e2);
  e0 *= inv; e1 *= inv; e2 *= inv;
  float acc[11];
#pragma unroll
  for (int o = 0; o < 11; ++o) acc[o] = 0.f;
#pragma unroll
  for (int c = 0; c < 3; ++c) {
    int i = tid + 256 * c;
    float sq = q[c] + e0 * o0[c] + e1 * o1[c] + e2 * o2[c];
#pragma unroll
    for (int g = 0; g < 3; ++g) {
      float sn, cs;
      __sincosf(sq * (float)(g + 1), &sn, &cs);
#pragma unroll
      for (int o = 0; o < 11; ++o)
        acc[o] += cs * coef[(size_t)(o * 3 + g) * DIM + i] +
                  sn * coef[(size_t)(33 + o * 3 + g) * DIM + i];
    }
  }
  __syncthreads();
#pragma unroll
  for (int o = 0; o < 11; ++o) {
    float v = acc[o];
#pragma unroll
    for (int off = 32; off; off >>= 1) v += __shfl_down(v, off);
    if (lane == 0) red[o][wid] = v;
  }
  __syncthreads();
  if (tid < 11)
    out[(size_t)p * 11 + tid] =
        red[tid][0] + red[tid][1] + red[tid][2] + red[tid][3] + kbias[tid];
}

extern "C" void kernel_launch(void* const* d_in, const int* in_sizes, int n_in,
                              void* d_out, int out_size, void* d_ws, size_t ws_size,
                              hipStream_t stream) {
  const float* seq = (const float*)d_in[0];
  const float* WihF = (const float*)d_in[1];
  const float* WhhF = (const float*)d_in[2];
  const float* bihF = (const float*)d_in[3];
  const float* bhhF = (const float*)d_in[4];
  const float* WihB = (const float*)d_in[5];
  const float* WhhB = (const float*)d_in[6];
  const float* bihB = (const float*)d_in[7];
  const float* bhhB = (const float*)d_in[8];
  const float* coef = (const float*)d_in[9];
  const float* kbias = (const float*)d_in[10];
  const int* valid = (const int*)d_in[11];

  constexpr size_t SZ_XC = (size_t)BT * DIM * 2;
  constexpr size_t SZ_DEST = (size_t)BT * 4;
  constexpr size_t GE = (size_t)3 * BT * NG;
  constexpr size_t CE = (size_t)3 * BT * HID;
  constexpr size_t HE = (size_t)3 * BT * HID;
  constexpr size_t SZ_OUTS = (size_t)3 * BT * DIM * 2;
  constexpr size_t SZ_WIHC = (size_t)2 * 3 * NG * DIM * 2;   // 14.16 MB
  constexpr size_t SZ_WHHC = (size_t)2 * 3 * NG * HID * 2;   // 7.08 MB
  auto need = [](int nd, int pre) {
    return SZ_XC + SZ_DEST + (size_t)pre * (SZ_WIHC + SZ_WHHC) +
           (size_t)nd * (GE * 2 + CE * 4 + HE * 2 * 2) + SZ_OUTS;
  };
  if (ws_size < need(1, 0)) return;
  int ndir, pre;
  if (ws_size >= need(2, 1))      { ndir = 2; pre = 1; }
  else if (ws_size >= need(2, 0)) { ndir = 2; pre = 0; }
  else if (ws_size >= need(1, 1)) { ndir = 1; pre = 1; }
  else                            { ndir = 1; pre = 0; }

  char* ws = (char*)d_ws;
  US* xc = (US*)ws;                          ws += SZ_XC;
  int* dest = (int*)ws;                      ws += SZ_DEST;
  US* WihC = (US*)ws;                        ws += pre ? SZ_WIHC : 0;
  US* WhhC = (US*)ws;                        ws += pre ? SZ_WHHC : 0;
  US* G = (US*)ws;                           ws += (size_t)ndir * GE * 2;
  float* C = (float*)ws;                     ws += (size_t)ndir * CE * 4;
  US* h0 = (US*)ws;                          ws += (size_t)ndir * HE * 2;
  US* h1 = (US*)ws;                          ws += (size_t)ndir * HE * 2;
  US* Outs = (US*)ws;
  float* out = (float*)d_out;

  hipMemsetAsync(xc, 0, SZ_XC, stream);
  scan_k<<<16, SEQL, 0, stream>>>(valid, dest);
  scatter_k<<<(BT * 192) / 256, 256, 0, stream>>>(seq, dest, xc);
  if (pre) {
    convW_ih_k<<<dim3(884736 / 256, 1, 2), 256, 0, stream>>>(WihF, WihB, WihC);
    convW_hh_k<<<dim3(442368 / 256, 1, 2), 256, 0, stream>>>(WhhF, WhhB, WhhC);
  }

  auto run_gate = [&](int z, size_t gs, int db) {
    if (pre)
      gate_gemm_k<true><<<dim3(64, 12, z), 256, 0, stream>>>(
          xc, WihF, WihB, WihC, bihF, bihB, bhhF, bhhB, G, gs, db);
    else
      gate_gemm_k<false><<<dim3(64, 12, z), 256, 0, stream>>>(
          xc, WihF, WihB, WihC, bihF, bihB, bhhF, bhhB, G, gs, db);
  };
  auto run_step = [&](int z, int s, int wi0, int nact, size_t gs, size_t cs, size_t hs, int db,
                      US* hcur, US* hnxt) {
    if (pre)
      step_k<true><<<dim3(64, 12, z), 256, 0, stream>>>(
          WhhF, WhhB, WhhC, G, C, hcur, hnxt, Outs, s, wi0, nact, gs, cs, hs, db);
    else
      step_k<false><<<dim3(64, 12, z), 256, 0, stream>>>(
          WhhF, WhhB, WhhC, G, C, hcur, hnxt, Outs, s, wi0, nact, gs, cs, hs, db);
  };

  if (ndir == 2) {
    run_gate(6, GE, 0);
    step0_k<<<dim3(BT, 1, 6), HID, 0, stream>>>(G, C, h1, GE, CE, HE, 0);
    for (int s = 1; s < 7; ++s) {
      int nact = (s < 3) ? 3 : ((s < 5) ? 2 : 1);
      int wi0 = 3 - nact;
      US* hcur = (s & 1) ? h1 : h0;
      US* hnxt = (s & 1) ? h0 : h1;
      run_step(nact * 2, s, wi0, nact, GE, CE, HE, 0, hcur, hnxt);
    }
  } else {
    for (int dir = 0; dir < 2; ++dir) {
      run_gate(3, 0, dir);
      step0_k<<<dim3(BT, 1, 3), HID, 0, stream>>>(G, C, h1, 0, 0, 0, dir);
      for (int s = 1; s < 7; ++s) {
        int nact = (s < 3) ? 3 : ((s < 5) ? 2 : 1);
        int wi0 = 3 - nact;
        US* hcur = (s & 1) ? h1 : h0;
        US* hnxt = (s & 1) ? h0 : h1;
        run_step(nact, s, wi0, nact, 0, 0, 0, dir, hcur, hnxt);
      }
    }
  }
  attn_kan_k<<<BT, 256, 0, stream>>>(Outs, coef, kbias, out);
}

// Round 5
// 1040.385 us; speedup vs baseline: 1.1983x; 1.0039x over previous
//
#include <hip/hip_runtime.h>

#define BT 8192     // B*L
#define SEQL 512
#define DIM 768
#define HID 384
#define NG 1536     // 4*HID

using US = unsigned short;
typedef __bf16 bf16x8 __attribute__((ext_vector_type(8)));
typedef float f32x4 __attribute__((ext_vector_type(4)));

__device__ __forceinline__ float b2f(US u) {
  union { unsigned u; float f; } x; x.u = ((unsigned)u) << 16; return x.f;
}
__device__ __forceinline__ US f2b(float f) {
  __bf16 h = (__bf16)f;
  union { __bf16 h; US u; } x; x.h = h; return x.u;
}
__device__ __forceinline__ float fsig(float x) { return 1.f / (1.f + __expf(-x)); }
__device__ __forceinline__ float ftanh(float x) { return 1.f - 2.f / (__expf(2.f * x) + 1.f); }

__device__ __forceinline__ void gload16(const void* g, void* l) {
  __builtin_amdgcn_global_load_lds((const __attribute__((address_space(1))) unsigned*)g,
                                   (__attribute__((address_space(3))) unsigned*)l, 16, 0, 0);
}

// swizzled LDS read: tile [128 rows][128 bytes], phys = row*128 + (colb ^ ((row&7)<<4))
__device__ __forceinline__ bf16x8 lds_frag(const US* base, int row, int colb, int swz) {
  return *(const bf16x8*)((const char*)base + row * 128 + (colb ^ swz));
}

// ---------------- weight pre-conversion ----------------
// Wih: gather into gate-tile order [dir][wi][nb(12)][r=sg*32+hh][DIM] bf16
__global__ __launch_bounds__(256) void convW_ih_k(const float* __restrict__ WihF,
                                                  const float* __restrict__ WihB,
                                                  US* __restrict__ WihC) {
  int d = blockIdx.z;
  const float* src = d ? WihB : WihF;
  size_t idx = (size_t)blockIdx.x * 256 + threadIdx.x;  // 884736 chunks per dir
  int c4 = (int)(idx % 192) * 4;
  int rr = (int)(idx / 192);                            // 0..4607
  int r = rr & 127;
  int nb = (rr >> 7) % 12;
  int wi = rr / (128 * 12);
  int srow = (r >> 5) * HID + nb * 32 + (r & 31);
  float4 v = *(const float4*)(src + ((size_t)wi * NG + srow) * DIM + c4);
  ushort4 o;
  o.x = f2b(v.x); o.y = f2b(v.y); o.z = f2b(v.z); o.w = f2b(v.w);
  *(ushort4*)(WihC + ((size_t)d * 4608 + rr) * DIM + c4) = o;
}

// Whh: gather into step-tile order [dir][wi][hb][r=sg*32+hh][K] bf16
__global__ __launch_bounds__(256) void convW_hh_k(const float* __restrict__ WhhF,
                                                  const float* __restrict__ WhhB,
                                                  US* __restrict__ WhhC) {
  int d = blockIdx.z;
  const float* src = d ? WhhB : WhhF;
  size_t idx = (size_t)blockIdx.x * 256 + threadIdx.x;  // 442368 chunks per dir
  int c4 = (int)(idx % 96) * 4;
  int rr = (int)(idx / 96);
  int r = rr & 127;
  int hb = (rr >> 7) % 12;
  int wi = rr / (128 * 12);
  int srow = (r >> 5) * HID + hb * 32 + (r & 31);
  float4 v = *(const float4*)(src + ((size_t)wi * NG + srow) * HID + c4);
  ushort4 o;
  o.x = f2b(v.x); o.y = f2b(v.y); o.z = f2b(v.z); o.w = f2b(v.w);
  *(ushort4*)(WhhC + ((size_t)d * 3 * 12 * 128 + (size_t)rr) * HID + c4) = o;
}

// ---------------- compaction ----------------
__global__ void scan_k(const int* __restrict__ valid, int* __restrict__ dest) {
  __shared__ int s[SEQL];
  int b = blockIdx.x, l = threadIdx.x;
  int v = (valid[b * SEQL + l] == 1) ? 1 : 0;
  s[l] = v;
  __syncthreads();
  for (int off = 1; off < SEQL; off <<= 1) {
    int t = (l >= off) ? s[l - off] : 0;
    __syncthreads();
    s[l] += t;
    __syncthreads();
  }
  dest[b * SEQL + l] = v ? (s[l] - 1) : -1;
}

__global__ __launch_bounds__(256) void scatter_k(const float* __restrict__ seq,
                                                 const int* __restrict__ dest,
                                                 US* __restrict__ xc) {
  int idx = blockIdx.x * 256 + threadIdx.x;  // BT*192 float4 chunks
  int p = idx / 192, c = idx - p * 192;
  int d = dest[p];
  if (d < 0) return;
  int b = p >> 9;
  float4 v = ((const float4*)seq)[(size_t)p * 192 + c];
  ushort4 o;
  o.x = f2b(v.x); o.y = f2b(v.y); o.z = f2b(v.z); o.w = f2b(v.w);
  ((ushort4*)xc)[(size_t)(b * SEQL + d) * 192 + c] = o;
}

// ---------------- gate pre-GEMM: G[dr][wi][p][hidx][4] = xc @ Wih^T + bias ----------------
// B-tile gathered {i,f,g,o}x32h like step_k; epilogue writes ushort4 per (row,h).
template <bool PRE>
__global__ __launch_bounds__(256) void gate_gemm_k(
    const US* __restrict__ xc,
    const float* __restrict__ WihF, const float* __restrict__ WihB,
    const US* __restrict__ WihC,
    const float* __restrict__ bihF, const float* __restrict__ bihB,
    const float* __restrict__ bhhF, const float* __restrict__ bhhB,
    US* __restrict__ G, size_t gStride, int dirBase) {
  int zi = blockIdx.z;
  int wi = zi % 3, dr = dirBase + zi / 3;
  const float* Wih = dr ? WihB : WihF;
  const float* bih = dr ? bihB : bihF;
  const float* bhh = dr ? bhhB : bhhF;
  const float* W = Wih + (size_t)wi * NG * DIM;
  int m0 = blockIdx.x * 128, nb = blockIdx.y;
  const US* Wp = WihC + ((size_t)(dr * 3 + wi) * 12 + nb) * 128 * DIM;
  US* Gw = G + (size_t)dr * gStride + (size_t)wi * BT * NG;
  __shared__ alignas(16) US As[2][128 * 64];
  __shared__ alignas(16) US Bs[2][128 * 64];
  __shared__ float biasS[128];
  int tid = threadIdx.x, lane = tid & 63, wid = tid >> 6;
  int wm = wid >> 1, wn = wid & 1;
  if (tid < 128) {
    int sg = tid >> 5, hl = tid & 31;
    int gc = wi * NG + sg * HID + nb * 32 + hl;
    biasS[tid] = bih[gc] + bhh[gc];
  }
  int r_in = lane >> 3;
  int cb = (lane & 7) * 16;
  int cb_src = cb ^ (r_in << 4);   // pre-swizzled global source column (bytes)
  int swz = (lane & 7) << 4;       // read-side swizzle
  f32x4 acc[4][4] = {};

  auto stageA = [&](US* dst, int k0) {
#pragma unroll
    for (int c = 0; c < 4; ++c) {
      int chk = wid * 4 + c;
      int row = chk * 8 + r_in;
      gload16((const char*)xc + ((size_t)(m0 + row) * DIM + k0) * 2 + cb_src,
              (char*)dst + chk * 1024);
    }
  };
  auto stageB = [&](US* dst, int k0) {
    if constexpr (PRE) {
#pragma unroll
      for (int c = 0; c < 4; ++c) {
        int chk = wid * 4 + c;
        int row = chk * 8 + r_in;
        gload16((const char*)Wp + ((size_t)row * DIM + k0) * 2 + cb_src,
                (char*)dst + chk * 1024);
      }
    } else {
#pragma unroll
      for (int j = 0; j < 8; ++j) {
        int q = j * 256 + tid;
        int row = q >> 4;
        int c4 = (q & 15) << 2;
        int srow = (row >> 5) * HID + nb * 32 + (row & 31);
        float4 v = *(const float4*)(W + (size_t)srow * DIM + k0 + c4);
        ushort4 o;
        o.x = f2b(v.x); o.y = f2b(v.y); o.z = f2b(v.z); o.w = f2b(v.w);
        *(ushort4*)((char*)dst + row * 128 + ((c4 * 2) ^ ((row & 7) << 4))) = o;
      }
    }
  };

  stageA(As[0], 0);
  stageB(Bs[0], 0);
  __syncthreads();
  int cur = 0;
  for (int k0 = 0; k0 < DIM; k0 += 64) {
    if (k0 + 64 < DIM) { stageA(As[cur ^ 1], k0 + 64); stageB(Bs[cur ^ 1], k0 + 64); }
#pragma unroll
    for (int kk = 0; kk < 2; ++kk) {
      int colb = kk * 64 + (lane >> 4) * 16;
      bf16x8 a[4], b[4];
#pragma unroll
      for (int i = 0; i < 4; ++i)
        a[i] = lds_frag(As[cur], wm * 64 + i * 16 + (lane & 15), colb, swz);
#pragma unroll
      for (int sg = 0; sg < 4; ++sg)
        b[sg] = lds_frag(Bs[cur], sg * 32 + wn * 16 + (lane & 15), colb, swz);
#pragma unroll
      for (int mi = 0; mi < 4; ++mi)
#pragma unroll
        for (int sg = 0; sg < 4; ++sg)
          acc[mi][sg] = __builtin_amdgcn_mfma_f32_16x16x32_bf16(a[mi], b[sg], acc[mi][sg], 0, 0, 0);
    }
    __syncthreads();
    cur ^= 1;
  }
  int hh = wn * 16 + (lane & 15);
  int hidx = nb * 32 + hh;
#pragma unroll
  for (int mi = 0; mi < 4; ++mi) {
#pragma unroll
    for (int r = 0; r < 4; ++r) {
      int p = m0 + wm * 64 + mi * 16 + ((lane >> 4) << 2) + r;
      ushort4 gv;
      gv.x = f2b(acc[mi][0][r] + biasS[hh]);
      gv.y = f2b(acc[mi][1][r] + biasS[32 + hh]);
      gv.z = f2b(acc[mi][2][r] + biasS[64 + hh]);
      gv.w = f2b(acc[mi][3][r] + biasS[96 + hh]);
      *(ushort4*)&Gw[(size_t)p * NG + (size_t)hidx * 4] = gv;
    }
  }
}

// ---------------- LSTM step 0 (h=0): pointwise only ----------------
__global__ __launch_bounds__(384) void step0_k(const US* __restrict__ G, float* __restrict__ C,
                                               US* __restrict__ hn,
                                               size_t gStride, size_t cStride, size_t hStride,
                                               int dirBase) {
  int zi = blockIdx.z;
  int wi = zi % 3, dr = dirBase + zi / 3;
  int half = wi + 1;
  int dlt = dr ? half : -half;
  int p = blockIdx.x, hidx = threadIdx.x;
  int l = p & (SEQL - 1);
  const US* Gw = G + (size_t)dr * gStride + (size_t)wi * BT * NG;
  float c = 0.f, h = 0.f;
  int t = l + dlt;
  if ((unsigned)t < (unsigned)SEQL) {
    ushort4 gv = *(const ushort4*)&Gw[(size_t)(p + dlt) * NG + (size_t)hidx * 4];
    c = fsig(b2f(gv.x)) * ftanh(b2f(gv.z));
    h = fsig(b2f(gv.w)) * ftanh(c);
  }
  size_t o = (size_t)wi * BT * HID + (size_t)p * HID + hidx;
  C[(size_t)dr * cStride + o] = c;
  hn[(size_t)dr * hStride + o] = f2b(h);
}

// ---------------- LSTM step s>=1: fused h@Whh^T GEMM + pointwise ----------------
template <bool PRE>
__global__ __launch_bounds__(256) void step_k(
    const float* __restrict__ WhhF, const float* __restrict__ WhhB,
    const US* __restrict__ WhhC,
    const US* __restrict__ G, float* __restrict__ C,
    const US* __restrict__ hcur, US* __restrict__ hnxt, US* __restrict__ Outs,
    int s, int wi0, int nact,
    size_t gStride, size_t cStride, size_t hStride, int dirBase) {
  int zi = blockIdx.z;
  int wi = wi0 + zi % nact, dr = dirBase + zi / nact;
  int w = 2 * wi + 3, half = wi + 1;
  int j = dr ? (w - 1 - s) : s;
  int dlt = j - half;
  bool fin = (s == w - 1);
  const float* Whh = dr ? WhhB : WhhF;
  const float* Wc = Whh + (size_t)wi * NG * HID;
  const US* Gw = G + (size_t)dr * gStride + (size_t)wi * BT * NG;
  float* Cw = C + (size_t)dr * cStride + (size_t)wi * BT * HID;
  const US* hc = hcur + (size_t)dr * hStride + (size_t)wi * BT * HID;
  US* hn = hnxt + (size_t)dr * hStride + (size_t)wi * BT * HID;
  US* Ow = Outs + (size_t)wi * BT * DIM + (dr ? HID : 0);
  int m0 = blockIdx.x * 128, hb = blockIdx.y;
  const US* Wp = WhhC + (size_t)((dr * 3 + wi) * 12 + hb) * 128 * HID;
  __shared__ alignas(16) US As[2][128 * 64];
  __shared__ alignas(16) US Bs[2][128 * 64];
  int tid = threadIdx.x, lane = tid & 63, wid = tid >> 6;
  int wm = wid >> 1, wn = wid & 1;
  int r_in = lane >> 3, cb = (lane & 7) * 16;
  int cb_src = cb ^ (r_in << 4);
  int swz = (lane & 7) << 4;
  f32x4 acc[4][4] = {};

  auto stageA = [&](US* dst, int k0) {
#pragma unroll
    for (int c = 0; c < 4; ++c) {
      int chk = wid * 4 + c;
      int row = chk * 8 + r_in;
      gload16((const char*)hc + ((size_t)(m0 + row) * HID + k0) * 2 + cb_src,
              (char*)dst + chk * 1024);
    }
  };
  auto stageB = [&](US* dst, int k0) {
    if constexpr (PRE) {
#pragma unroll
      for (int c = 0; c < 4; ++c) {
        int chk = wid * 4 + c;
        int row = chk * 8 + r_in;
        gload16((const char*)Wp + ((size_t)row * HID + k0) * 2 + cb_src,
                (char*)dst + chk * 1024);
      }
    } else {
#pragma unroll
      for (int j2 = 0; j2 < 8; ++j2) {
        int q = j2 * 256 + tid;
        int row = q >> 4;
        int c4 = (q & 15) << 2;
        int srow = (row >> 5) * HID + hb * 32 + (row & 31);
        float4 v = *(const float4*)(Wc + (size_t)srow * HID + k0 + c4);
        ushort4 o;
        o.x = f2b(v.x); o.y = f2b(v.y); o.z = f2b(v.z); o.w = f2b(v.w);
        *(ushort4*)((char*)dst + row * 128 + ((c4 * 2) ^ ((row & 7) << 4))) = o;
      }
    }
  };

  stageA(As[0], 0);
  stageB(Bs[0], 0);
  __syncthreads();
  int cur = 0;
  for (int k0 = 0; k0 < HID; k0 += 64) {
    if (k0 + 64 < HID) { stageA(As[cur ^ 1], k0 + 64); stageB(Bs[cur ^ 1], k0 + 64); }
#pragma unroll
    for (int kk = 0; kk < 2; ++kk) {
      int colb = kk * 64 + (lane >> 4) * 16;
      bf16x8 a[4], b[4];
#pragma unroll
      for (int i = 0; i < 4; ++i)
        a[i] = lds_frag(As[cur], wm * 64 + i * 16 + (lane & 15), colb, swz);
#pragma unroll
      for (int sg = 0; sg < 4; ++sg)
        b[sg] = lds_frag(Bs[cur], sg * 32 + wn * 16 + (lane & 15), colb, swz);
#pragma unroll
      for (int mi = 0; mi < 4; ++mi)
#pragma unroll
        for (int sg = 0; sg < 4; ++sg)
          acc[mi][sg] = __builtin_amdgcn_mfma_f32_16x16x32_bf16(a[mi], b[sg], acc[mi][sg], 0, 0, 0);
    }
    __syncthreads();
    cur ^= 1;
  }
  int hh = wn * 16 + (lane & 15);
  int hidx = hb * 32 + hh;
#pragma unroll
  for (int mi = 0; mi < 4; ++mi) {
#pragma unroll
    for (int r = 0; r < 4; ++r) {
      int p = m0 + wm * 64 + mi * 16 + ((lane >> 4) << 2) + r;
      int l = p & (SEQL - 1);
      float hval;
      if ((unsigned)(l + dlt) < (unsigned)SEQL) {
        ushort4 gv = *(const ushort4*)&Gw[(size_t)(p + dlt) * NG + (size_t)hidx * 4];
        float gi = acc[mi][0][r] + b2f(gv.x);
        float gf = acc[mi][1][r] + b2f(gv.y);
        float gg = acc[mi][2][r] + b2f(gv.z);
        float go = acc[mi][3][r] + b2f(gv.w);
        size_t ci = (size_t)p * HID + hidx;
        float c = fsig(gf) * Cw[ci] + fsig(gi) * ftanh(gg);
        Cw[ci] = c;
        hval = fsig(go) * ftanh(c);
      } else {
        hval = b2f(hc[(size_t)p * HID + hidx]);
      }
      if (fin) Ow[(size_t)p * DIM + hidx] = f2b(hval);
      else hn[(size_t)p * HID + hidx] = f2b(hval);
    }
  }
}

// ---------------- attention over 3 windows + KAN head (4 tokens / block) ----------------
__global__ __launch_bounds__(256) void attn_kan_k(
    const US* __restrict__ Outs, const float* __restrict__ coef,
    const float* __restrict__ kbias, float* __restrict__ out) {
  int p4 = blockIdx.x * 4;
  int tid = threadIdx.x, lane = tid & 63, wid = tid >> 6;
  __shared__ float red[192];
  float o0[3][4], o1[3][4], o2[3][4], q[3][4];
#pragma unroll
  for (int c = 0; c < 3; ++c) {
    int i = tid + 256 * c;
#pragma unroll
    for (int t = 0; t < 4; ++t) {
      o0[c][t] = b2f(Outs[(size_t)(p4 + t) * DIM + i]);
      o1[c][t] = b2f(Outs[(size_t)(BT + p4 + t) * DIM + i]);
      o2[c][t] = b2f(Outs[(size_t)(2 * BT + p4 + t) * DIM + i]);
      q[c][t] = o0[c][t] + o1[c][t] + o2[c][t];
    }
  }
  float d[3][4];
#pragma unroll
  for (int t = 0; t < 4; ++t) {
    d[0][t] = 0.f; d[1][t] = 0.f; d[2][t] = 0.f;
#pragma unroll
    for (int c = 0; c < 3; ++c) {
      d[0][t] += q[c][t] * o0[c][t];
      d[1][t] += q[c][t] * o1[c][t];
      d[2][t] += q[c][t] * o2[c][t];
    }
  }
#pragma unroll
  for (int off = 32; off; off >>= 1)
#pragma unroll
    for (int t = 0; t < 4; ++t) {
      d[0][t] += __shfl_down(d[0][t], off);
      d[1][t] += __shfl_down(d[1][t], off);
      d[2][t] += __shfl_down(d[2][t], off);
    }
  if (lane == 0)
#pragma unroll
    for (int t = 0; t < 4; ++t) {
      red[(t * 3 + 0) * 4 + wid] = d[0][t];
      red[(t * 3 + 1) * 4 + wid] = d[1][t];
      red[(t * 3 + 2) * 4 + wid] = d[2][t];
    }
  __syncthreads();
  const float scl = 0.03608439182435161f;  // 1/sqrt(768)
  float e0[4], e1[4], e2[4];
#pragma unroll
  for (int t = 0; t < 4; ++t) {
    float s0 = (red[(t * 3) * 4] + red[(t * 3) * 4 + 1] + red[(t * 3) * 4 + 2] + red[(t * 3) * 4 + 3]) * scl;
    float s1 = (red[(t * 3 + 1) * 4] + red[(t * 3 + 1) * 4 + 1] + red[(t * 3 + 1) * 4 + 2] + red[(t * 3 + 1) * 4 + 3]) * scl;
    float s2 = (red[(t * 3 + 2) * 4] + red[(t * 3 + 2) * 4 + 1] + red[(t * 3 + 2) * 4 + 2] + red[(t * 3 + 2) * 4 + 3]) * scl;
    float mx = fmaxf(s0, fmaxf(s1, s2));
    float a0 = __expf(s0 - mx), a1 = __expf(s1 - mx), a2 = __expf(s2 - mx);
    float inv = 1.f / (a0 + a1 + a2);
    e0[t] = a0 * inv; e1[t] = a1 * inv; e2[t] = a2 * inv;
  }
  float sq[3][4];
#pragma unroll
  for (int c = 0; c < 3; ++c)
#pragma unroll
    for (int t = 0; t < 4; ++t)
      sq[c][t] = q[c][t] + e0[t] * o0[c][t] + e1[t] * o1[c][t] + e2[t] * o2[c][t];
  float acc[11][4];
#pragma unroll
  for (int o = 0; o < 11; ++o)
#pragma unroll
    for (int t = 0; t < 4; ++t) acc[o][t] = 0.f;
#pragma unroll
  for (int c = 0; c < 3; ++c) {
    int i = tid + 256 * c;
#pragma unroll
    for (int g = 0; g < 3; ++g) {
      float sn[4], cs[4];
#pragma unroll
      for (int t = 0; t < 4; ++t) __sincosf(sq[c][t] * (float)(g + 1), &sn[t], &cs[t]);
#pragma unroll
      for (int o = 0; o < 11; ++o) {
        float cc = coef[(size_t)(o * 3 + g) * DIM + i];
        float ss = coef[(size_t)(33 + o * 3 + g) * DIM + i];
#pragma unroll
        for (int t = 0; t < 4; ++t) acc[o][t] += cs[t] * cc + sn[t] * ss;
      }
    }
  }
  __syncthreads();
#pragma unroll
  for (int o = 0; o < 11; ++o)
#pragma unroll
    for (int t = 0; t < 4; ++t) {
      float v = acc[o][t];
#pragma unroll
      for (int off = 32; off; off >>= 1) v += __shfl_down(v, off);
      if (lane == 0) red[(o * 4 + t) * 4 + wid] = v;
    }
  __syncthreads();
  if (tid < 44) {
    int o = tid >> 2, t = tid & 3;
    out[(size_t)(p4 + t) * 11 + o] =
        red[tid * 4] + red[tid * 4 + 1] + red[tid * 4 + 2] + red[tid * 4 + 3] + kbias[o];
  }
}

extern "C" void kernel_launch(void* const* d_in, const int* in_sizes, int n_in,
                              void* d_out, int out_size, void* d_ws, size_t ws_size,
                              hipStream_t stream) {
  const float* seq = (const float*)d_in[0];
  const float* WihF = (const float*)d_in[1];
  const float* WhhF = (const float*)d_in[2];
  const float* bihF = (const float*)d_in[3];
  const float* bhhF = (const float*)d_in[4];
  const float* WihB = (const float*)d_in[5];
  const float* WhhB = (const float*)d_in[6];
  const float* bihB = (const float*)d_in[7];
  const float* bhhB = (const float*)d_in[8];
  const float* coef = (const float*)d_in[9];
  const float* kbias = (const float*)d_in[10];
  const int* valid = (const int*)d_in[11];

  constexpr size_t SZ_XC = (size_t)BT * DIM * 2;
  constexpr size_t SZ_DEST = (size_t)BT * 4;
  constexpr size_t GE = (size_t)3 * BT * NG;
  constexpr size_t CE = (size_t)3 * BT * HID;
  constexpr size_t HE = (size_t)3 * BT * HID;
  constexpr size_t SZ_OUTS = (size_t)3 * BT * DIM * 2;
  constexpr size_t SZ_WIHC = (size_t)2 * 3 * NG * DIM * 2;   // 14.16 MB
  constexpr size_t SZ_WHHC = (size_t)2 * 3 * NG * HID * 2;   // 7.08 MB
  auto need = [](int nd, int pre) {
    return SZ_XC + SZ_DEST + (size_t)pre * (SZ_WIHC + SZ_WHHC) +
           (size_t)nd * (GE * 2 + CE * 4 + HE * 2 * 2) + SZ_OUTS;
  };
  if (ws_size < need(1, 0)) return;
  int ndir, pre;
  if (ws_size >= need(2, 1))      { ndir = 2; pre = 1; }
  else if (ws_size >= need(2, 0)) { ndir = 2; pre = 0; }
  else if (ws_size >= need(1, 1)) { ndir = 1; pre = 1; }
  else                            { ndir = 1; pre = 0; }

  char* ws = (char*)d_ws;
  US* xc = (US*)ws;                          ws += SZ_XC;
  int* dest = (int*)ws;                      ws += SZ_DEST;
  US* WihC = (US*)ws;                        ws += pre ? SZ_WIHC : 0;
  US* WhhC = (US*)ws;                        ws += pre ? SZ_WHHC : 0;
  US* G = (US*)ws;                           ws += (size_t)ndir * GE * 2;
  float* C = (float*)ws;                     ws += (size_t)ndir * CE * 4;
  US* h0 = (US*)ws;                          ws += (size_t)ndir * HE * 2;
  US* h1 = (US*)ws;                          ws += (size_t)ndir * HE * 2;
  US* Outs = (US*)ws;
  float* out = (float*)d_out;

  hipMemsetAsync(xc, 0, SZ_XC, stream);
  scan_k<<<16, SEQL, 0, stream>>>(valid, dest);
  scatter_k<<<(BT * 192) / 256, 256, 0, stream>>>(seq, dest, xc);
  if (pre) {
    convW_ih_k<<<dim3(884736 / 256, 1, 2), 256, 0, stream>>>(WihF, WihB, WihC);
    convW_hh_k<<<dim3(442368 / 256, 1, 2), 256, 0, stream>>>(WhhF, WhhB, WhhC);
  }

  auto run_gate = [&](int z, size_t gs, int db) {
    if (pre)
      gate_gemm_k<true><<<dim3(64, 12, z), 256, 0, stream>>>(
          xc, WihF, WihB, WihC, bihF, bihB, bhhF, bhhB, G, gs, db);
    else
      gate_gemm_k<false><<<dim3(64, 12, z), 256, 0, stream>>>(
          xc, WihF, WihB, WihC, bihF, bihB, bhhF, bhhB, G, gs, db);
  };
  auto run_step = [&](int z, int s, int wi0, int nact, size_t gs, size_t cs, size_t hs, int db,
                      US* hcur, US* hnxt) {
    if (pre)
      step_k<true><<<dim3(64, 12, z), 256, 0, stream>>>(
          WhhF, WhhB, WhhC, G, C, hcur, hnxt, Outs, s, wi0, nact, gs, cs, hs, db);
    else
      step_k<false><<<dim3(64, 12, z), 256, 0, stream>>>(
          WhhF, WhhB, WhhC, G, C, hcur, hnxt, Outs, s, wi0, nact, gs, cs, hs, db);
  };

  if (ndir == 2) {
    run_gate(6, GE, 0);
    step0_k<<<dim3(BT, 1, 6), HID, 0, stream>>>(G, C, h1, GE, CE, HE, 0);
    for (int s = 1; s < 7; ++s) {
      int nact = (s < 3) ? 3 : ((s < 5) ? 2 : 1);
      int wi0 = 3 - nact;
      US* hcur = (s & 1) ? h1 : h0;
      US* hnxt = (s & 1) ? h0 : h1;
      run_step(nact * 2, s, wi0, nact, GE, CE, HE, 0, hcur, hnxt);
    }
  } else {
    for (int dir = 0; dir < 2; ++dir) {
      run_gate(3, 0, dir);
      step0_k<<<dim3(BT, 1, 3), HID, 0, stream>>>(G, C, h1, 0, 0, 0, dir);
      for (int s = 1; s < 7; ++s) {
        int nact = (s < 3) ? 3 : ((s < 5) ? 2 : 1);
        int wi0 = 3 - nact;
        US* hcur = (s & 1) ? h1 : h0;
        US* hnxt = (s & 1) ? h0 : h1;
        run_step(nact, s, wi0, nact, 0, 0, 0, dir, hcur, hnxt);
      }
    }
  }
  attn_kan_k<<<BT / 4, 256, 0, stream>>>(Outs, coef, kbias, out);
}

// Round 6
// 980.039 us; speedup vs baseline: 1.2720x; 1.0616x over previous
//
#include <hip/hip_runtime.h>

#define BT 8192     // B*L
#define SEQL 512
#define DIM 768
#define HID 384
#define NG 1536     // 4*HID

using US = unsigned short;
typedef __bf16 bf16x8 __attribute__((ext_vector_type(8)));
typedef float f32x4 __attribute__((ext_vector_type(4)));

__device__ __forceinline__ float b2f(US u) {
  union { unsigned u; float f; } x; x.u = ((unsigned)u) << 16; return x.f;
}
__device__ __forceinline__ US f2b(float f) {
  __bf16 h = (__bf16)f;
  union { __bf16 h; US u; } x; x.h = h; return x.u;
}
__device__ __forceinline__ float fsig(float x) { return 1.f / (1.f + __expf(-x)); }
__device__ __forceinline__ float ftanh(float x) { return 1.f - 2.f / (__expf(2.f * x) + 1.f); }

__device__ __forceinline__ void gload16(const void* g, void* l) {
  __builtin_amdgcn_global_load_lds((const __attribute__((address_space(1))) unsigned*)g,
                                   (__attribute__((address_space(3))) unsigned*)l, 16, 0, 0);
}

// swizzled LDS read: tile [128 rows][128 bytes], phys = row*128 + (colb ^ ((row&7)<<4))
__device__ __forceinline__ bf16x8 lds_frag(const US* base, int row, int colb, int swz) {
  return *(const bf16x8*)((const char*)base + row * 128 + (colb ^ swz));
}

// ---------------- weight pre-conversion ----------------
// Wih: gather into gate-tile order [dir][wi][nb(12)][r=sg*32+hh][DIM] bf16
__global__ __launch_bounds__(256) void convW_ih_k(const float* __restrict__ WihF,
                                                  const float* __restrict__ WihB,
                                                  US* __restrict__ WihC) {
  int d = blockIdx.z;
  const float* src = d ? WihB : WihF;
  size_t idx = (size_t)blockIdx.x * 256 + threadIdx.x;  // 884736 chunks per dir
  int c4 = (int)(idx % 192) * 4;
  int rr = (int)(idx / 192);                            // 0..4607
  int r = rr & 127;
  int nb = (rr >> 7) % 12;
  int wi = rr / (128 * 12);
  int srow = (r >> 5) * HID + nb * 32 + (r & 31);
  float4 v = *(const float4*)(src + ((size_t)wi * NG + srow) * DIM + c4);
  ushort4 o;
  o.x = f2b(v.x); o.y = f2b(v.y); o.z = f2b(v.z); o.w = f2b(v.w);
  *(ushort4*)(WihC + ((size_t)d * 4608 + rr) * DIM + c4) = o;
}

// Whh: gather into step-tile order [dir][wi][hb][r=sg*32+hh][K] bf16
__global__ __launch_bounds__(256) void convW_hh_k(const float* __restrict__ WhhF,
                                                  const float* __restrict__ WhhB,
                                                  US* __restrict__ WhhC) {
  int d = blockIdx.z;
  const float* src = d ? WhhB : WhhF;
  size_t idx = (size_t)blockIdx.x * 256 + threadIdx.x;  // 442368 chunks per dir
  int c4 = (int)(idx % 96) * 4;
  int rr = (int)(idx / 96);
  int r = rr & 127;
  int hb = (rr >> 7) % 12;
  int wi = rr / (128 * 12);
  int srow = (r >> 5) * HID + hb * 32 + (r & 31);
  float4 v = *(const float4*)(src + ((size_t)wi * NG + srow) * HID + c4);
  ushort4 o;
  o.x = f2b(v.x); o.y = f2b(v.y); o.z = f2b(v.z); o.w = f2b(v.w);
  *(ushort4*)(WhhC + ((size_t)d * 3 * 12 * 128 + (size_t)rr) * HID + c4) = o;
}

// KAN coef: pack into [g][i][32] bf16: slots 0..10 = cos coefs (o), 16..26 = sin coefs
__global__ __launch_bounds__(256) void conv_coef_k(const float* __restrict__ coef,
                                                   US* __restrict__ coefP) {
  int idx = blockIdx.x * 256 + threadIdx.x;  // 3*768*32 = 73728
  int s = idx & 31;
  int i = (idx >> 5) % DIM;
  int g = idx / (32 * DIM);
  float v = 0.f;
  int o = s & 15;
  if (o < 11) v = coef[(size_t)((s >> 4) * 33 + o * 3 + g) * DIM + i];
  coefP[idx] = f2b(v);
}

// ---------------- compaction ----------------
__global__ void scan_k(const int* __restrict__ valid, int* __restrict__ dest) {
  __shared__ int s[SEQL];
  int b = blockIdx.x, l = threadIdx.x;
  int v = (valid[b * SEQL + l] == 1) ? 1 : 0;
  s[l] = v;
  __syncthreads();
  for (int off = 1; off < SEQL; off <<= 1) {
    int t = (l >= off) ? s[l - off] : 0;
    __syncthreads();
    s[l] += t;
    __syncthreads();
  }
  dest[b * SEQL + l] = v ? (s[l] - 1) : -1;
}

__global__ __launch_bounds__(256) void scatter_k(const float* __restrict__ seq,
                                                 const int* __restrict__ dest,
                                                 US* __restrict__ xc) {
  int idx = blockIdx.x * 256 + threadIdx.x;  // BT*192 float4 chunks
  int p = idx / 192, c = idx - p * 192;
  int d = dest[p];
  if (d < 0) return;
  int b = p >> 9;
  float4 v = ((const float4*)seq)[(size_t)p * 192 + c];
  ushort4 o;
  o.x = f2b(v.x); o.y = f2b(v.y); o.z = f2b(v.z); o.w = f2b(v.w);
  ((ushort4*)xc)[(size_t)(b * SEQL + d) * 192 + c] = o;
}

// ---------------- gate pre-GEMM: G[dr][wi][p][hidx][4] = xc @ Wih^T + bias ----------------
template <bool PRE>
__global__ __launch_bounds__(256) void gate_gemm_k(
    const US* __restrict__ xc,
    const float* __restrict__ WihF, const float* __restrict__ WihB,
    const US* __restrict__ WihC,
    const float* __restrict__ bihF, const float* __restrict__ bihB,
    const float* __restrict__ bhhF, const float* __restrict__ bhhB,
    US* __restrict__ G, size_t gStride, int dirBase) {
  int zi = blockIdx.z;
  int wi = zi % 3, dr = dirBase + zi / 3;
  const float* Wih = dr ? WihB : WihF;
  const float* bih = dr ? bihB : bihF;
  const float* bhh = dr ? bhhB : bhhF;
  const float* W = Wih + (size_t)wi * NG * DIM;
  int m0 = blockIdx.x * 128, nb = blockIdx.y;
  const US* Wp = WihC + ((size_t)(dr * 3 + wi) * 12 + nb) * 128 * DIM;
  US* Gw = G + (size_t)dr * gStride + (size_t)wi * BT * NG;
  __shared__ alignas(16) US As[2][128 * 64];
  __shared__ alignas(16) US Bs[2][128 * 64];
  __shared__ float biasS[128];
  int tid = threadIdx.x, lane = tid & 63, wid = tid >> 6;
  int wm = wid >> 1, wn = wid & 1;
  if (tid < 128) {
    int sg = tid >> 5, hl = tid & 31;
    int gc = wi * NG + sg * HID + nb * 32 + hl;
    biasS[tid] = bih[gc] + bhh[gc];
  }
  int r_in = lane >> 3;
  int cb = (lane & 7) * 16;
  int cb_src = cb ^ (r_in << 4);   // pre-swizzled global source column (bytes)
  int swz = (lane & 7) << 4;       // read-side swizzle
  f32x4 acc[4][4] = {};

  auto stageA = [&](US* dst, int k0) {
#pragma unroll
    for (int c = 0; c < 4; ++c) {
      int chk = wid * 4 + c;
      int row = chk * 8 + r_in;
      gload16((const char*)xc + ((size_t)(m0 + row) * DIM + k0) * 2 + cb_src,
              (char*)dst + chk * 1024);
    }
  };
  auto stageB = [&](US* dst, int k0) {
    if constexpr (PRE) {
#pragma unroll
      for (int c = 0; c < 4; ++c) {
        int chk = wid * 4 + c;
        int row = chk * 8 + r_in;
        gload16((const char*)Wp + ((size_t)row * DIM + k0) * 2 + cb_src,
                (char*)dst + chk * 1024);
      }
    } else {
#pragma unroll
      for (int j = 0; j < 8; ++j) {
        int q = j * 256 + tid;
        int row = q >> 4;
        int c4 = (q & 15) << 2;
        int srow = (row >> 5) * HID + nb * 32 + (row & 31);
        float4 v = *(const float4*)(W + (size_t)srow * DIM + k0 + c4);
        ushort4 o;
        o.x = f2b(v.x); o.y = f2b(v.y); o.z = f2b(v.z); o.w = f2b(v.w);
        *(ushort4*)((char*)dst + row * 128 + ((c4 * 2) ^ ((row & 7) << 4))) = o;
      }
    }
  };

  stageA(As[0], 0);
  stageB(Bs[0], 0);
  __syncthreads();
  int cur = 0;
  for (int k0 = 0; k0 < DIM; k0 += 64) {
    if (k0 + 64 < DIM) { stageA(As[cur ^ 1], k0 + 64); stageB(Bs[cur ^ 1], k0 + 64); }
#pragma unroll
    for (int kk = 0; kk < 2; ++kk) {
      int colb = kk * 64 + (lane >> 4) * 16;
      bf16x8 a[4], b[4];
#pragma unroll
      for (int i = 0; i < 4; ++i)
        a[i] = lds_frag(As[cur], wm * 64 + i * 16 + (lane & 15), colb, swz);
#pragma unroll
      for (int sg = 0; sg < 4; ++sg)
        b[sg] = lds_frag(Bs[cur], sg * 32 + wn * 16 + (lane & 15), colb, swz);
#pragma unroll
      for (int mi = 0; mi < 4; ++mi)
#pragma unroll
        for (int sg = 0; sg < 4; ++sg)
          acc[mi][sg] = __builtin_amdgcn_mfma_f32_16x16x32_bf16(a[mi], b[sg], acc[mi][sg], 0, 0, 0);
    }
    __syncthreads();
    cur ^= 1;
  }
  int hh = wn * 16 + (lane & 15);
  int hidx = nb * 32 + hh;
#pragma unroll
  for (int mi = 0; mi < 4; ++mi) {
#pragma unroll
    for (int r = 0; r < 4; ++r) {
      int p = m0 + wm * 64 + mi * 16 + ((lane >> 4) << 2) + r;
      ushort4 gv;
      gv.x = f2b(acc[mi][0][r] + biasS[hh]);
      gv.y = f2b(acc[mi][1][r] + biasS[32 + hh]);
      gv.z = f2b(acc[mi][2][r] + biasS[64 + hh]);
      gv.w = f2b(acc[mi][3][r] + biasS[96 + hh]);
      *(ushort4*)&Gw[(size_t)p * NG + (size_t)hidx * 4] = gv;
    }
  }
}

// ---------------- LSTM step 0 (h=0): pointwise only (C stored bf16) ----------------
__global__ __launch_bounds__(384) void step0_k(const US* __restrict__ G, US* __restrict__ C,
                                               US* __restrict__ hn,
                                               size_t gStride, size_t cStride, size_t hStride,
                                               int dirBase) {
  int zi = blockIdx.z;
  int wi = zi % 3, dr = dirBase + zi / 3;
  int half = wi + 1;
  int dlt = dr ? half : -half;
  int p = blockIdx.x, hidx = threadIdx.x;
  int l = p & (SEQL - 1);
  const US* Gw = G + (size_t)dr * gStride + (size_t)wi * BT * NG;
  float c = 0.f, h = 0.f;
  int t = l + dlt;
  if ((unsigned)t < (unsigned)SEQL) {
    ushort4 gv = *(const ushort4*)&Gw[(size_t)(p + dlt) * NG + (size_t)hidx * 4];
    c = fsig(b2f(gv.x)) * ftanh(b2f(gv.z));
    h = fsig(b2f(gv.w)) * ftanh(c);
  }
  size_t o = (size_t)wi * BT * HID + (size_t)p * HID + hidx;
  C[(size_t)dr * cStride + o] = f2b(c);
  hn[(size_t)dr * hStride + o] = f2b(h);
}

// ---------------- LSTM step s>=1: fused h@Whh^T GEMM + pointwise ----------------
template <bool PRE>
__global__ __launch_bounds__(256) void step_k(
    const float* __restrict__ WhhF, const float* __restrict__ WhhB,
    const US* __restrict__ WhhC,
    const US* __restrict__ G, US* __restrict__ C,
    const US* __restrict__ hcur, US* __restrict__ hnxt, US* __restrict__ Outs,
    int s, int wi0, int nact,
    size_t gStride, size_t cStride, size_t hStride, int dirBase) {
  int zi = blockIdx.z;
  int wi = wi0 + zi % nact, dr = dirBase + zi / nact;
  int w = 2 * wi + 3, half = wi + 1;
  int j = dr ? (w - 1 - s) : s;
  int dlt = j - half;
  bool fin = (s == w - 1);
  const float* Whh = dr ? WhhB : WhhF;
  const float* Wc = Whh + (size_t)wi * NG * HID;
  const US* Gw = G + (size_t)dr * gStride + (size_t)wi * BT * NG;
  US* Cw = C + (size_t)dr * cStride + (size_t)wi * BT * HID;
  const US* hc = hcur + (size_t)dr * hStride + (size_t)wi * BT * HID;
  US* hn = hnxt + (size_t)dr * hStride + (size_t)wi * BT * HID;
  US* Ow = Outs + (size_t)wi * BT * DIM + (dr ? HID : 0);
  int m0 = blockIdx.x * 128, hb = blockIdx.y;
  const US* Wp = WhhC + (size_t)((dr * 3 + wi) * 12 + hb) * 128 * HID;
  __shared__ alignas(16) US As[2][128 * 64];
  __shared__ alignas(16) US Bs[2][128 * 64];
  int tid = threadIdx.x, lane = tid & 63, wid = tid >> 6;
  int wm = wid >> 1, wn = wid & 1;
  int r_in = lane >> 3, cb = (lane & 7) * 16;
  int cb_src = cb ^ (r_in << 4);
  int swz = (lane & 7) << 4;
  f32x4 acc[4][4] = {};

  auto stageA = [&](US* dst, int k0) {
#pragma unroll
    for (int c = 0; c < 4; ++c) {
      int chk = wid * 4 + c;
      int row = chk * 8 + r_in;
      gload16((const char*)hc + ((size_t)(m0 + row) * HID + k0) * 2 + cb_src,
              (char*)dst + chk * 1024);
    }
  };
  auto stageB = [&](US* dst, int k0) {
    if constexpr (PRE) {
#pragma unroll
      for (int c = 0; c < 4; ++c) {
        int chk = wid * 4 + c;
        int row = chk * 8 + r_in;
        gload16((const char*)Wp + ((size_t)row * HID + k0) * 2 + cb_src,
                (char*)dst + chk * 1024);
      }
    } else {
#pragma unroll
      for (int j2 = 0; j2 < 8; ++j2) {
        int q = j2 * 256 + tid;
        int row = q >> 4;
        int c4 = (q & 15) << 2;
        int srow = (row >> 5) * HID + hb * 32 + (row & 31);
        float4 v = *(const float4*)(Wc + (size_t)srow * HID + k0 + c4);
        ushort4 o;
        o.x = f2b(v.x); o.y = f2b(v.y); o.z = f2b(v.z); o.w = f2b(v.w);
        *(ushort4*)((char*)dst + row * 128 + ((c4 * 2) ^ ((row & 7) << 4))) = o;
      }
    }
  };

  stageA(As[0], 0);
  stageB(Bs[0], 0);
  __syncthreads();
  int cur = 0;
  for (int k0 = 0; k0 < HID; k0 += 64) {
    if (k0 + 64 < HID) { stageA(As[cur ^ 1], k0 + 64); stageB(Bs[cur ^ 1], k0 + 64); }
#pragma unroll
    for (int kk = 0; kk < 2; ++kk) {
      int colb = kk * 64 + (lane >> 4) * 16;
      bf16x8 a[4], b[4];
#pragma unroll
      for (int i = 0; i < 4; ++i)
        a[i] = lds_frag(As[cur], wm * 64 + i * 16 + (lane & 15), colb, swz);
#pragma unroll
      for (int sg = 0; sg < 4; ++sg)
        b[sg] = lds_frag(Bs[cur], sg * 32 + wn * 16 + (lane & 15), colb, swz);
#pragma unroll
      for (int mi = 0; mi < 4; ++mi)
#pragma unroll
        for (int sg = 0; sg < 4; ++sg)
          acc[mi][sg] = __builtin_amdgcn_mfma_f32_16x16x32_bf16(a[mi], b[sg], acc[mi][sg], 0, 0, 0);
    }
    __syncthreads();
    cur ^= 1;
  }
  int hh = wn * 16 + (lane & 15);
  int hidx = hb * 32 + hh;
#pragma unroll
  for (int mi = 0; mi < 4; ++mi) {
#pragma unroll
    for (int r = 0; r < 4; ++r) {
      int p = m0 + wm * 64 + mi * 16 + ((lane >> 4) << 2) + r;
      int l = p & (SEQL - 1);
      float hval;
      if ((unsigned)(l + dlt) < (unsigned)SEQL) {
        ushort4 gv = *(const ushort4*)&Gw[(size_t)(p + dlt) * NG + (size_t)hidx * 4];
        float gi = acc[mi][0][r] + b2f(gv.x);
        float gf = acc[mi][1][r] + b2f(gv.y);
        float gg = acc[mi][2][r] + b2f(gv.z);
        float go = acc[mi][3][r] + b2f(gv.w);
        size_t ci = (size_t)p * HID + hidx;
        float c = fsig(gf) * b2f(Cw[ci]) + fsig(gi) * ftanh(gg);
        Cw[ci] = f2b(c);
        hval = fsig(go) * ftanh(c);
      } else {
        hval = b2f(hc[(size_t)p * HID + hidx]);
      }
      if (fin) Ow[(size_t)p * DIM + hidx] = f2b(hval);
      else hn[(size_t)p * HID + hidx] = f2b(hval);
    }
  }
}

// ---------------- attention over 3 windows + KAN head (4 tokens / block) ----------------
// coefP: [g][i][32] bf16 (slots 0..10 cos, 16..26 sin) -> 4x 16B loads per (c,g)
__global__ __launch_bounds__(256) void attn_kan_k(
    const US* __restrict__ Outs, const US* __restrict__ coefP,
    const float* __restrict__ kbias, float* __restrict__ out) {
  int p4 = blockIdx.x * 4;
  int tid = threadIdx.x, lane = tid & 63, wid = tid >> 6;
  __shared__ float red[176];
  float sq[3][4];
  {
    float o0[3][4], o1[3][4], o2[3][4], q[3][4];
#pragma unroll
    for (int c = 0; c < 3; ++c) {
      int i = tid + 256 * c;
#pragma unroll
      for (int t = 0; t < 4; ++t) {
        o0[c][t] = b2f(Outs[(size_t)(p4 + t) * DIM + i]);
        o1[c][t] = b2f(Outs[(size_t)(BT + p4 + t) * DIM + i]);
        o2[c][t] = b2f(Outs[(size_t)(2 * BT + p4 + t) * DIM + i]);
        q[c][t] = o0[c][t] + o1[c][t] + o2[c][t];
      }
    }
    float d[3][4];
#pragma unroll
    for (int t = 0; t < 4; ++t) {
      d[0][t] = 0.f; d[1][t] = 0.f; d[2][t] = 0.f;
#pragma unroll
      for (int c = 0; c < 3; ++c) {
        d[0][t] += q[c][t] * o0[c][t];
        d[1][t] += q[c][t] * o1[c][t];
        d[2][t] += q[c][t] * o2[c][t];
      }
    }
#pragma unroll
    for (int off = 32; off; off >>= 1)
#pragma unroll
      for (int t = 0; t < 4; ++t) {
        d[0][t] += __shfl_down(d[0][t], off);
        d[1][t] += __shfl_down(d[1][t], off);
        d[2][t] += __shfl_down(d[2][t], off);
      }
    if (lane == 0)
#pragma unroll
      for (int t = 0; t < 4; ++t) {
        red[(t * 3 + 0) * 4 + wid] = d[0][t];
        red[(t * 3 + 1) * 4 + wid] = d[1][t];
        red[(t * 3 + 2) * 4 + wid] = d[2][t];
      }
    __syncthreads();
    const float scl = 0.03608439182435161f;  // 1/sqrt(768)
#pragma unroll
    for (int t = 0; t < 4; ++t) {
      float s0 = (red[(t * 3) * 4] + red[(t * 3) * 4 + 1] + red[(t * 3) * 4 + 2] + red[(t * 3) * 4 + 3]) * scl;
      float s1 = (red[(t * 3 + 1) * 4] + red[(t * 3 + 1) * 4 + 1] + red[(t * 3 + 1) * 4 + 2] + red[(t * 3 + 1) * 4 + 3]) * scl;
      float s2 = (red[(t * 3 + 2) * 4] + red[(t * 3 + 2) * 4 + 1] + red[(t * 3 + 2) * 4 + 2] + red[(t * 3 + 2) * 4 + 3]) * scl;
      float mx = fmaxf(s0, fmaxf(s1, s2));
      float a0 = __expf(s0 - mx), a1 = __expf(s1 - mx), a2 = __expf(s2 - mx);
      float inv = 1.f / (a0 + a1 + a2);
      a0 *= inv; a1 *= inv; a2 *= inv;
#pragma unroll
      for (int c = 0; c < 3; ++c)
        sq[c][t] = q[c][t] + a0 * o0[c][t] + a1 * o1[c][t] + a2 * o2[c][t];
    }
  }
  float acc[11][4];
#pragma unroll
  for (int o = 0; o < 11; ++o)
#pragma unroll
    for (int t = 0; t < 4; ++t) acc[o][t] = 0.f;
#pragma unroll
  for (int c = 0; c < 3; ++c) {
    int i = tid + 256 * c;
#pragma unroll
    for (int g = 0; g < 3; ++g) {
      float sn[4], cs[4];
#pragma unroll
      for (int t = 0; t < 4; ++t) __sincosf(sq[c][t] * (float)(g + 1), &sn[t], &cs[t]);
      const US* cp = coefP + ((size_t)g * DIM + i) * 32;
      bf16x8 k0 = *(const bf16x8*)(cp);
      bf16x8 k1 = *(const bf16x8*)(cp + 8);
      bf16x8 k2 = *(const bf16x8*)(cp + 16);
      bf16x8 k3 = *(const bf16x8*)(cp + 24);
#pragma unroll
      for (int o = 0; o < 8; ++o) {
        float cc = (float)k0[o], ss = (float)k2[o];
#pragma unroll
        for (int t = 0; t < 4; ++t) acc[o][t] += cs[t] * cc + sn[t] * ss;
      }
#pragma unroll
      for (int o = 8; o < 11; ++o) {
        float cc = (float)k1[o - 8], ss = (float)k3[o - 8];
#pragma unroll
        for (int t = 0; t < 4; ++t) acc[o][t] += cs[t] * cc + sn[t] * ss;
      }
    }
  }
  __syncthreads();
#pragma unroll
  for (int o = 0; o < 11; ++o)
#pragma unroll
    for (int t = 0; t < 4; ++t) {
      float v = acc[o][t];
#pragma unroll
      for (int off = 32; off; off >>= 1) v += __shfl_down(v, off);
      if (lane == 0) red[(o * 4 + t) * 4 + wid] = v;
    }
  __syncthreads();
  if (tid < 44) {
    int o = tid >> 2, t = tid & 3;
    out[(size_t)(p4 + t) * 11 + o] =
        red[tid * 4] + red[tid * 4 + 1] + red[tid * 4 + 2] + red[tid * 4 + 3] + kbias[o];
  }
}

extern "C" void kernel_launch(void* const* d_in, const int* in_sizes, int n_in,
                              void* d_out, int out_size, void* d_ws, size_t ws_size,
                              hipStream_t stream) {
  const float* seq = (const float*)d_in[0];
  const float* WihF = (const float*)d_in[1];
  const float* WhhF = (const float*)d_in[2];
  const float* bihF = (const float*)d_in[3];
  const float* bhhF = (const float*)d_in[4];
  const float* WihB = (const float*)d_in[5];
  const float* WhhB = (const float*)d_in[6];
  const float* bihB = (const float*)d_in[7];
  const float* bhhB = (const float*)d_in[8];
  const float* coef = (const float*)d_in[9];
  const float* kbias = (const float*)d_in[10];
  const int* valid = (const int*)d_in[11];

  constexpr size_t SZ_XC = (size_t)BT * DIM * 2;
  constexpr size_t SZ_DEST = (size_t)BT * 4;
  constexpr size_t SZ_CP = (size_t)3 * DIM * 32 * 2;         // 0.14 MB packed coef
  constexpr size_t GE = (size_t)3 * BT * NG;
  constexpr size_t CE = (size_t)3 * BT * HID;                // bf16 now
  constexpr size_t HE = (size_t)3 * BT * HID;
  constexpr size_t SZ_OUTS = (size_t)3 * BT * DIM * 2;
  constexpr size_t SZ_WIHC = (size_t)2 * 3 * NG * DIM * 2;   // 14.16 MB
  constexpr size_t SZ_WHHC = (size_t)2 * 3 * NG * HID * 2;   // 7.08 MB
  auto need = [](int nd, int pre) {
    return SZ_XC + SZ_DEST + SZ_CP + (size_t)pre * (SZ_WIHC + SZ_WHHC) +
           (size_t)nd * (GE * 2 + CE * 2 + HE * 2 * 2) + SZ_OUTS;
  };
  if (ws_size < need(1, 0)) return;
  int ndir, pre;
  if (ws_size >= need(2, 1))      { ndir = 2; pre = 1; }
  else if (ws_size >= need(2, 0)) { ndir = 2; pre = 0; }
  else if (ws_size >= need(1, 1)) { ndir = 1; pre = 1; }
  else                            { ndir = 1; pre = 0; }

  char* ws = (char*)d_ws;
  US* xc = (US*)ws;                          ws += SZ_XC;
  int* dest = (int*)ws;                      ws += SZ_DEST;
  US* coefP = (US*)ws;                       ws += SZ_CP;
  US* WihC = (US*)ws;                        ws += pre ? SZ_WIHC : 0;
  US* WhhC = (US*)ws;                        ws += pre ? SZ_WHHC : 0;
  US* G = (US*)ws;                           ws += (size_t)ndir * GE * 2;
  US* C = (US*)ws;                           ws += (size_t)ndir * CE * 2;
  US* h0 = (US*)ws;                          ws += (size_t)ndir * HE * 2;
  US* h1 = (US*)ws;                          ws += (size_t)ndir * HE * 2;
  US* Outs = (US*)ws;
  float* out = (float*)d_out;

  hipMemsetAsync(xc, 0, SZ_XC, stream);
  scan_k<<<16, SEQL, 0, stream>>>(valid, dest);
  scatter_k<<<(BT * 192) / 256, 256, 0, stream>>>(seq, dest, xc);
  conv_coef_k<<<288, 256, 0, stream>>>(coef, coefP);
  if (pre) {
    convW_ih_k<<<dim3(884736 / 256, 1, 2), 256, 0, stream>>>(WihF, WihB, WihC);
    convW_hh_k<<<dim3(442368 / 256, 1, 2), 256, 0, stream>>>(WhhF, WhhB, WhhC);
  }

  auto run_gate = [&](int z, size_t gs, int db) {
    if (pre)
      gate_gemm_k<true><<<dim3(64, 12, z), 256, 0, stream>>>(
          xc, WihF, WihB, WihC, bihF, bihB, bhhF, bhhB, G, gs, db);
    else
      gate_gemm_k<false><<<dim3(64, 12, z), 256, 0, stream>>>(
          xc, WihF, WihB, WihC, bihF, bihB, bhhF, bhhB, G, gs, db);
  };
  auto run_step = [&](int z, int s, int wi0, int nact, size_t gs, size_t cs, size_t hs, int db,
                      US* hcur, US* hnxt) {
    if (pre)
      step_k<true><<<dim3(64, 12, z), 256, 0, stream>>>(
          WhhF, WhhB, WhhC, G, C, hcur, hnxt, Outs, s, wi0, nact, gs, cs, hs, db);
    else
      step_k<false><<<dim3(64, 12, z), 256, 0, stream>>>(
          WhhF, WhhB, WhhC, G, C, hcur, hnxt, Outs, s, wi0, nact, gs, cs, hs, db);
  };

  if (ndir == 2) {
    run_gate(6, GE, 0);
    step0_k<<<dim3(BT, 1, 6), HID, 0, stream>>>(G, C, h1, GE, CE, HE, 0);
    for (int s = 1; s < 7; ++s) {
      int nact = (s < 3) ? 3 : ((s < 5) ? 2 : 1);
      int wi0 = 3 - nact;
      US* hcur = (s & 1) ? h1 : h0;
      US* hnxt = (s & 1) ? h0 : h1;
      run_step(nact * 2, s, wi0, nact, GE, CE, HE, 0, hcur, hnxt);
    }
  } else {
    for (int dir = 0; dir < 2; ++dir) {
      run_gate(3, 0, dir);
      step0_k<<<dim3(BT, 1, 3), HID, 0, stream>>>(G, C, h1, 0, 0, 0, dir);
      for (int s = 1; s < 7; ++s) {
        int nact = (s < 3) ? 3 : ((s < 5) ? 2 : 1);
        int wi0 = 3 - nact;
        US* hcur = (s & 1) ? h1 : h0;
        US* hnxt = (s & 1) ? h0 : h1;
        run_step(nact, s, wi0, nact, 0, 0, 0, dir, hcur, hnxt);
      }
    }
  }
  attn_kan_k<<<BT / 4, 256, 0, stream>>>(Outs, coefP, kbias, out);
}